// Round 8
// baseline (1232.050 us; speedup 1.0000x reference)
//
#include <hip/hip_runtime.h>
#include <hip/hip_bf16.h>
#include <math.h>

#define B_ 8
#define C_ 128
#define H_ 64
#define W_ 64
#define HW_ 4096
#define HEADS_ 8
#define CH_ 16
#define HID_ 512

typedef unsigned short ushort_t;
struct us4 { ushort_t x, y, z, w; };

__device__ __forceinline__ float bf2f(ushort_t u) {
  return __uint_as_float(((unsigned int)u) << 16);
}
__device__ __forceinline__ ushort_t f2bu(float f) {
  __hip_bfloat16 h = __float2bfloat16(f);
  return *reinterpret_cast<ushort_t*>(&h);
}

// ---------------- LayerNorm over channel dim ----------------
__global__ __launch_bounds__(256) void ln_ch(const float* __restrict__ x,
                                             const float* __restrict__ w,
                                             const float* __restrict__ b,
                                             float* __restrict__ out) {
  int p = blockIdx.x * 256 + threadIdx.x;  // over B*HW
  int bi = p >> 12;
  int pos = p & (HW_ - 1);
  const float* xb = x + (size_t)bi * C_ * HW_ + pos;
  float s = 0.f, ss = 0.f;
  for (int c = 0; c < C_; c++) {
    float v = xb[(size_t)c * HW_];
    s += v;
    ss = fmaf(v, v, ss);
  }
  float mu = s * (1.f / C_);
  float var = ss * (1.f / C_) - mu * mu;
  float inv = rsqrtf(var + 1e-5f);
  float* ob = out + (size_t)bi * C_ * HW_ + pos;
  for (int c = 0; c < C_; c++) {
    ob[(size_t)c * HW_] = (xb[(size_t)c * HW_] - mu) * inv * w[c] + b[c];
  }
}

// ---------------- vector load/store helpers ----------------
__device__ __forceinline__ void load4f(const float* p, float* v) {
  float4 t = *(const float4*)p;
  v[0] = t.x; v[1] = t.y; v[2] = t.z; v[3] = t.w;
}
__device__ __forceinline__ void load4f(const __hip_bfloat16* p, float* v) {
  us4 t = *(const us4*)p;
  v[0] = bf2f(t.x); v[1] = bf2f(t.y); v[2] = bf2f(t.z); v[3] = bf2f(t.w);
}
__device__ __forceinline__ void store4f(float* p, const float* v) {
  float4 t; t.x = v[0]; t.y = v[1]; t.z = v[2]; t.w = v[3];
  *(float4*)p = t;
}
__device__ __forceinline__ void store4f(__hip_bfloat16* p, const float* v) {
  us4 t; t.x = f2bu(v[0]); t.y = f2bu(v[1]); t.z = f2bu(v[2]); t.w = f2bu(v[3]);
  *(us4*)p = t;
}

// ------- conv1x1 (GEMM over channels), 16 outputs x 4 positions, LDS weights -------
template <int CIN, typename Tin, typename Tout>
__global__ __launch_bounds__(256) void conv1x1_v(const Tin* __restrict__ in,
                                                 const float* __restrict__ wt,
                                                 const float* __restrict__ resid,
                                                 Tout* __restrict__ out,
                                                 int cout, int wstride, int accum) {
  __shared__ float wsh[CIN * 16];
  int tid = threadIdx.x;
  int blk = blockIdx.x;
  int pb = blk & 3;  // 4 position blocks of 1024
  int t = blk >> 2;
  int nob = cout >> 4;
  int ob = t % nob;
  int bi = t / nob;
  int pos = (pb << 10) + tid * 4;
  int o0 = ob << 4;
  for (int l = tid; l < CIN * 16; l += 256) {
    int c = l >> 4, j = l & 15;
    wsh[l] = wt[(size_t)(o0 + j) * wstride + c];
  }
  __syncthreads();

  const Tin* ib = in + (size_t)bi * CIN * HW_ + pos;
  float acc[16][4] = {};
#pragma unroll 4
  for (int c = 0; c < CIN; c++) {
    float xv[4];
    load4f(ib + (size_t)c * HW_, xv);
    const float* wr = &wsh[c * 16];
#pragma unroll
    for (int j = 0; j < 16; j++) {
      float wv = wr[j];
      acc[j][0] = fmaf(wv, xv[0], acc[j][0]);
      acc[j][1] = fmaf(wv, xv[1], acc[j][1]);
      acc[j][2] = fmaf(wv, xv[2], acc[j][2]);
      acc[j][3] = fmaf(wv, xv[3], acc[j][3]);
    }
  }
  Tout* op = out + ((size_t)bi * cout + o0) * HW_ + pos;
  const float* rp = resid ? resid + ((size_t)bi * cout + o0) * HW_ + pos : nullptr;
#pragma unroll
  for (int j = 0; j < 16; j++) {
    float v[4];
    v[0] = acc[j][0]; v[1] = acc[j][1]; v[2] = acc[j][2]; v[3] = acc[j][3];
    if (rp) {
      float rv[4];
      load4f(rp + (size_t)j * HW_, rv);
      for (int q = 0; q < 4; q++) v[q] += rv[q];
    }
    if (accum) {
      float ov[4];
      load4f(op + (size_t)j * HW_, ov);
      for (int q = 0; q < 4; q++) v[q] += ov[q];
    }
    store4f(op + (size_t)j * HW_, v);
  }
}

// ------- depthwise conv, half-plane per 256-thread block, 8 out/thread -------
// 256-thread blocks: allocator behaves (R5: no spill); 8 out/thread: small live set.
template <int K>
__global__ __launch_bounds__(256) void dwconv_t(const float* __restrict__ q0,
                                                const float* __restrict__ k0,
                                                const float* __restrict__ v0,
                                                const float* __restrict__ wq_,
                                                const float* __restrict__ wk_,
                                                const float* __restrict__ wv_,
                                                float* __restrict__ qd,
                                                float* __restrict__ kd,
                                                float* __restrict__ vd) {
  constexpr int P = K / 2;
  constexpr int NR = 32 + 2 * P;       // staged rows (half plane + halo)
  constexpr int ST = 64 + 2 * P + 1;   // padded row stride
  __shared__ float img[NR * ST];
  __shared__ float wsh[K * K];
  int sel = blockIdx.y;
  const float* in = (sel == 0) ? q0 : (sel == 1) ? k0 : v0;
  const float* wgt = (sel == 0) ? wq_ : (sel == 1) ? wk_ : wv_;
  float* outp = (sel == 0) ? qd : (sel == 1) ? kd : vd;
  int blk = blockIdx.x;  // B*C*2
  int half = blk & 1;
  int c = (blk >> 1) & (C_ - 1);
  int bi = blk >> 8;
  int tid = threadIdx.x;

  for (int l = tid; l < NR * ST; l += 256) img[l] = 0.f;
  if (tid < K * K) wsh[tid] = wgt[(size_t)c * K * K + tid];
  __syncthreads();

  const float* ib = in + (size_t)(bi * C_ + c) * HW_;
  int r0 = half * 32;
  for (int l = tid; l < NR * 16; l += 256) {
    int rr = l >> 4;         // staged row 0..NR-1
    int gq = l & 15;
    int grow = r0 - P + rr;  // global row
    if ((unsigned)grow < 64u) {
      float4 v = ((const float4*)(ib + grow * 64))[gq];
      float* d = &img[rr * ST + P + gq * 4];
      d[0] = v.x; d[1] = v.y; d[2] = v.z; d[3] = v.w;
    }
  }
  __syncthreads();

  int r = tid >> 3;           // local row 0..31
  int cb = (tid & 7) << 3;    // col block 0..56
  float a[8];
#pragma unroll
  for (int o = 0; o < 8; o++) a[o] = 0.f;
#pragma unroll
  for (int dy = 0; dy < K; dy++) {
    const float* row = &img[(r + dy) * ST + cb];
    float rv[8 + 2 * P];
#pragma unroll
    for (int t = 0; t < 8 + 2 * P; t++) rv[t] = row[t];
#pragma unroll
    for (int dx = 0; dx < K; dx++) {
      float wv = wsh[dy * K + dx];
#pragma unroll
      for (int o = 0; o < 8; o++) a[o] = fmaf(rv[o + dx], wv, a[o]);
    }
  }
  float* ob = outp + (size_t)(bi * C_ + c) * HW_ + (r0 + r) * 64 + cb;
  store4f(ob, &a[0]);
  store4f(ob + 4, &a[4]);
}

// ------- FFN depthwise conv + GEGLU gate, half-plane, two-phase, 8 out/thread -------
template <int K>
__global__ __launch_bounds__(256) void ffn_dwgate_t(const __hip_bfloat16* __restrict__ xin,
                                                    const float* __restrict__ w,
                                                    __hip_bfloat16* __restrict__ gated) {
  constexpr int P = K / 2;
  constexpr int NR = 32 + 2 * P;
  constexpr int ST = 64 + 2 * P + 1;
  __shared__ float img[NR * ST];
  __shared__ float wsh[2 * K * K];
  int blk = blockIdx.x;  // B*512*2
  int half = blk & 1;
  int i = (blk >> 1) & 511;
  int bi = blk >> 10;
  int tid = threadIdx.x;

  if (tid < 2 * K * K) {
    wsh[tid] = (tid < K * K) ? w[(size_t)i * K * K + tid]
                             : w[(size_t)(512 + i) * K * K + (tid - K * K)];
  }
  for (int l = tid; l < NR * ST; l += 256) img[l] = 0.f;
  __syncthreads();

  const __hip_bfloat16* gin = xin + (size_t)(bi * 1024 + i) * HW_;
  const __hip_bfloat16* min_ = gin + (size_t)512 * HW_;
  int r0 = half * 32;
  int r = tid >> 3;
  int cb = (tid & 7) << 3;

  // ---- phase 1: gate plane ----
  for (int l = tid; l < NR * 16; l += 256) {
    int rr = l >> 4;
    int gq = l & 15;
    int grow = r0 - P + rr;
    if ((unsigned)grow < 64u) {
      us4 gv = ((const us4*)(gin + grow * 64))[gq];
      float* gd = &img[rr * ST + P + gq * 4];
      gd[0] = bf2f(gv.x); gd[1] = bf2f(gv.y); gd[2] = bf2f(gv.z); gd[3] = bf2f(gv.w);
    }
  }
  __syncthreads();

  float ge[8];
  {
    float a[8];
#pragma unroll
    for (int o = 0; o < 8; o++) a[o] = 0.f;
#pragma unroll
    for (int dy = 0; dy < K; dy++) {
      const float* row = &img[(r + dy) * ST + cb];
      float rv[8 + 2 * P];
#pragma unroll
      for (int t = 0; t < 8 + 2 * P; t++) rv[t] = row[t];
#pragma unroll
      for (int dx = 0; dx < K; dx++) {
        float wv = wsh[dy * K + dx];
#pragma unroll
        for (int o = 0; o < 8; o++) a[o] = fmaf(rv[o + dx], wv, a[o]);
      }
    }
#pragma unroll
    for (int o = 0; o < 8; o++)
      ge[o] = 0.5f * a[o] * (1.f + erff(a[o] * 0.70710678118654752f));
  }
  __syncthreads();  // all reads of g-plane done

  // ---- phase 2: mult plane into same LDS (borders still zero) ----
  for (int l = tid; l < NR * 16; l += 256) {
    int rr = l >> 4;
    int gq = l & 15;
    int grow = r0 - P + rr;
    if ((unsigned)grow < 64u) {
      us4 mv = ((const us4*)(min_ + grow * 64))[gq];
      float* md = &img[rr * ST + P + gq * 4];
      md[0] = bf2f(mv.x); md[1] = bf2f(mv.y); md[2] = bf2f(mv.z); md[3] = bf2f(mv.w);
    }
  }
  __syncthreads();

  float ma[8];
#pragma unroll
  for (int o = 0; o < 8; o++) ma[o] = 0.f;
#pragma unroll
  for (int dy = 0; dy < K; dy++) {
    const float* row = &img[(r + dy) * ST + cb];
    float rv[8 + 2 * P];
#pragma unroll
    for (int t = 0; t < 8 + 2 * P; t++) rv[t] = row[t];
#pragma unroll
    for (int dx = 0; dx < K; dx++) {
      float wv = wsh[K * K + dy * K + dx];
#pragma unroll
      for (int o = 0; o < 8; o++) ma[o] = fmaf(rv[o + dx], wv, ma[o]);
    }
  }
  __hip_bfloat16* gp = gated + (size_t)(bi * 512 + i) * HW_ + (r0 + r) * 64 + cb;
#pragma unroll
  for (int v = 0; v < 2; v++) {
    us4 t;
    t.x = f2bu(ge[v * 4 + 0] * ma[v * 4 + 0]);
    t.y = f2bu(ge[v * 4 + 1] * ma[v * 4 + 1]);
    t.z = f2bu(ge[v * 4 + 2] * ma[v * 4 + 2]);
    t.w = f2bu(ge[v * 4 + 3] * ma[v * 4 + 3]);
    *(us4*)(gp + v * 4) = t;
  }
}

// ---------------- inverse L2 norms of qd and kd rows ----------------
__global__ __launch_bounds__(256) void l2_invnorm(const float* __restrict__ qd,
                                                  const float* __restrict__ kd,
                                                  float* __restrict__ invn) {
  int row = blockIdx.x;  // 0..2047; <1024 -> qd, else kd
  const float* src = (row < 1024) ? (qd + (size_t)row * HW_)
                                  : (kd + (size_t)(row - 1024) * HW_);
  float s = 0.f;
  for (int n = threadIdx.x; n < HW_; n += 256) {
    float v = src[n];
    s = fmaf(v, v, s);
  }
#pragma unroll
  for (int o = 32; o >= 1; o >>= 1) s += __shfl_xor(s, o, 64);
  __shared__ float red[4];
  if ((threadIdx.x & 63) == 0) red[threadIdx.x >> 6] = s;
  __syncthreads();
  if (threadIdx.x == 0) {
    float t = red[0] + red[1] + red[2] + red[3];
    invn[row] = 1.f / fmaxf(sqrtf(t), 1e-12f);
  }
}

// ---------------- attention: partial scores over 256-position chunks ----------------
__global__ __launch_bounds__(256) void attn_score_part(const float* __restrict__ qd,
                                                       const float* __restrict__ kd,
                                                       float* __restrict__ part) {
  constexpr int ST = 258;
  __shared__ float qs[16 * ST];
  __shared__ float ks[16 * ST];
  int bh = blockIdx.x;   // 64
  int ch = blockIdx.y;   // 16 chunks of 256
  int bi = bh >> 3;
  int h = bh & 7;
  int tid = threadIdx.x;
  int c = tid >> 4;
  int d = tid & 15;

  const float* qrow = qd + (size_t)(bi * C_ + h * CH_) * HW_ + ch * 256;
  const float* krow = kd + (size_t)(bi * C_ + h * CH_) * HW_ + ch * 256;
#pragma unroll
  for (int it = 0; it < 4; it++) {
    int idx = tid + it * 256;
    int r = idx >> 6, q4 = idx & 63;
    float4 qv = ((const float4*)(qrow + (size_t)r * HW_))[q4];
    float4 kv = ((const float4*)(krow + (size_t)r * HW_))[q4];
    float* qdst = &qs[r * ST + q4 * 4];
    float* kdst = &ks[r * ST + q4 * 4];
    qdst[0] = qv.x; qdst[1] = qv.y; qdst[2] = qv.z; qdst[3] = qv.w;
    kdst[0] = kv.x; kdst[1] = kv.y; kdst[2] = kv.z; kdst[3] = kv.w;
  }
  __syncthreads();

  const float* qp = &qs[c * ST];
  const float* kp = &ks[d * ST];
  float acc = 0.f;
#pragma unroll 8
  for (int j = 0; j < 256; j++) acc = fmaf(qp[j], kp[j], acc);
  part[((size_t)bh * 16 + ch) * 256 + tid] = acc;
}

// ---------------- attention: reduce partials + softmax ----------------
__global__ __launch_bounds__(256) void attn_softmax(const float* __restrict__ part,
                                                    const float* __restrict__ invn,
                                                    const float* __restrict__ temp,
                                                    float* __restrict__ as_buf) {
  int bh = blockIdx.x;  // 64
  int bi = bh >> 3;
  int h = bh & 7;
  int tid = threadIdx.x;
  int c = tid >> 4;
  int d = tid & 15;
  float s = 0.f;
  const float* pp = part + (size_t)bh * 16 * 256 + tid;
#pragma unroll
  for (int ch = 0; ch < 16; ch++) s += pp[ch * 256];
  float S = s * invn[bi * C_ + h * CH_ + c] * invn[1024 + bi * C_ + h * CH_ + d] *
            temp[h];
  float mx = S;
#pragma unroll
  for (int o = 8; o >= 1; o >>= 1) mx = fmaxf(mx, __shfl_xor(mx, o, 16));
  float e = expf(S - mx);
  float sm = e;
#pragma unroll
  for (int o = 8; o >= 1; o >>= 1) sm += __shfl_xor(sm, o, 16);
  as_buf[(size_t)bh * 256 + tid] = e / sm;
}

// ---------------- attention: PV over 256-position chunks ----------------
__global__ __launch_bounds__(256) void attn_pv(const float* __restrict__ vd,
                                               const float* __restrict__ as_buf,
                                               float* __restrict__ osb) {
  __shared__ float as[16][17];
  int bh = blockIdx.x;  // 64
  int ch = blockIdx.y;  // 16
  int bi = bh >> 3;
  int h = bh & 7;
  int tid = threadIdx.x;
  if (tid < 256) {
    int cc = tid >> 4, dd = tid & 15;
    as[cc][dd] = as_buf[(size_t)bh * 256 + tid];
  }
  __syncthreads();

  int n = ch * 256 + tid;
  const float* vrow = vd + (size_t)(bi * C_ + h * CH_) * HW_ + n;
  float o_[16];
#pragma unroll
  for (int cc = 0; cc < 16; cc++) o_[cc] = 0.f;
#pragma unroll
  for (int dd = 0; dd < 16; dd++) {
    float vv = vrow[(size_t)dd * HW_];
#pragma unroll
    for (int cc = 0; cc < 16; cc++) o_[cc] = fmaf(as[cc][dd], vv, o_[cc]);
  }
  float* ob = osb + (size_t)(bi * C_ + h * CH_) * HW_ + n;
#pragma unroll
  for (int cc = 0; cc < 16; cc++) ob[(size_t)cc * HW_] = o_[cc];
}

extern "C" void kernel_launch(void* const* d_in, const int* in_sizes, int n_in,
                              void* d_out, int out_size, void* d_ws, size_t ws_size,
                              hipStream_t stream) {
  const float* x = (const float*)d_in[0];
  const float* ln1_w = (const float*)d_in[1];
  const float* ln1_b = (const float*)d_in[2];
  const float* temp = (const float*)d_in[3];
  const float* wq = (const float*)d_in[4];
  const float* wk = (const float*)d_in[5];
  const float* wv = (const float*)d_in[6];
  const float* dw[9];
  for (int i = 0; i < 9; i++) dw[i] = (const float*)d_in[7 + i];
  const float* attn_po = (const float*)d_in[16];
  const float* ln2_w = (const float*)d_in[17];
  const float* ln2_b = (const float*)d_in[18];
  const float* ffn_in = (const float*)d_in[19];
  const float* ffn_dw[3] = {(const float*)d_in[20], (const float*)d_in[21],
                            (const float*)d_in[22]};
  const float* ffn_po = (const float*)d_in[23];
  float* out = (float*)d_out;

  // ---- workspace layout: peak 128 MiB + 72 KiB, lifetime-aliased ----
  const size_t MB = (size_t)1 << 20;
  char* wsb = (char*)d_ws;
  float* xn = (float*)(wsb + 0 * MB);
  float* q0 = (float*)(wsb + 16 * MB);
  float* k0 = (float*)(wsb + 32 * MB);
  float* v0 = (float*)(wsb + 48 * MB);
  float* qd = (float*)(wsb + 64 * MB);
  float* kd = (float*)(wsb + 80 * MB);
  float* vd = (float*)(wsb + 96 * MB);
  float* x2 = (float*)(wsb + 112 * MB);
  float* invn = (float*)(wsb + 128 * MB);               // 8 KiB
  float* as_buf = (float*)(wsb + 128 * MB + 8 * 1024);  // 64 KiB
  float* osb = xn;
  float* xn2 = xn;
  float* part = xn;  // 4 MB partial-score buffer; dead before osb is written
  __hip_bfloat16* xin = (__hip_bfloat16*)(wsb + 16 * MB);    // 64 MB
  __hip_bfloat16* gated = (__hip_bfloat16*)(wsb + 80 * MB);  // 32 MB

  const int ln_grid = (B_ * HW_) / 256;                  // 128
  const int c128_grid = B_ * (C_ / 16) * 4;              // 256
  const int c1024_grid = B_ * (1024 / 16) * 4;           // 2048
  const dim3 dwt_grid(B_ * C_ * 2, 3);                   // 2048 x 3
  const int ffg_grid = B_ * 512 * 2;                     // 8192
  const dim3 att_grid(B_ * HEADS_, 16);                  // 64 x 16

  // ---- attention branch ----
  ln_ch<<<ln_grid, 256, 0, stream>>>(x, ln1_w, ln1_b, xn);
  conv1x1_v<C_, float, float><<<c128_grid, 256, 0, stream>>>(xn, wq, nullptr, q0, C_, C_, 0);
  conv1x1_v<C_, float, float><<<c128_grid, 256, 0, stream>>>(xn, wk, nullptr, k0, C_, C_, 0);
  conv1x1_v<C_, float, float><<<c128_grid, 256, 0, stream>>>(xn, wv, nullptr, v0, C_, C_, 0);

  for (int s = 0; s < 3; s++) {
    if (s == 0)
      dwconv_t<3><<<dwt_grid, 256, 0, stream>>>(q0, k0, v0, dw[0], dw[1], dw[2], qd, kd, vd);
    else if (s == 1)
      dwconv_t<5><<<dwt_grid, 256, 0, stream>>>(q0, k0, v0, dw[3], dw[4], dw[5], qd, kd, vd);
    else
      dwconv_t<7><<<dwt_grid, 256, 0, stream>>>(q0, k0, v0, dw[6], dw[7], dw[8], qd, kd, vd);
    l2_invnorm<<<2048, 256, 0, stream>>>(qd, kd, invn);
    attn_score_part<<<att_grid, 256, 0, stream>>>(qd, kd, part);
    attn_softmax<<<B_ * HEADS_, 256, 0, stream>>>(part, invn, temp, as_buf);
    attn_pv<<<att_grid, 256, 0, stream>>>(vd, as_buf, osb);
    conv1x1_v<C_, float, float><<<c128_grid, 256, 0, stream>>>(
        osb, attn_po + s * C_, (s == 0) ? x : nullptr, x2, C_, 3 * C_, s == 0 ? 0 : 1);
  }

  // ---- FFN branch ----
  ln_ch<<<ln_grid, 256, 0, stream>>>(x2, ln2_w, ln2_b, xn2);
  conv1x1_v<C_, float, __hip_bfloat16><<<c1024_grid, 256, 0, stream>>>(
      xn2, ffn_in, nullptr, xin, 1024, C_, 0);

  for (int s = 0; s < 3; s++) {
    if (s == 0)
      ffn_dwgate_t<3><<<ffg_grid, 256, 0, stream>>>(xin, ffn_dw[0], gated);
    else if (s == 1)
      ffn_dwgate_t<5><<<ffg_grid, 256, 0, stream>>>(xin, ffn_dw[1], gated);
    else
      ffn_dwgate_t<7><<<ffg_grid, 256, 0, stream>>>(xin, ffn_dw[2], gated);
    conv1x1_v<512, __hip_bfloat16, float><<<c128_grid, 256, 0, stream>>>(
        gated, ffn_po + s * 512, (s == 0) ? x2 : nullptr, out, C_, 3 * HID_,
        s == 0 ? 0 : 1);
  }
  (void)in_sizes; (void)n_in; (void)out_size; (void)ws_size;
}

// Round 9
// 1124.104 us; speedup vs baseline: 1.0960x; 1.0960x over previous
//
#include <hip/hip_runtime.h>
#include <hip/hip_bf16.h>
#include <math.h>

#define B_ 8
#define C_ 128
#define H_ 64
#define W_ 64
#define HW_ 4096
#define HEADS_ 8
#define CH_ 16
#define HID_ 512

typedef unsigned short ushort_t;
struct us4 { ushort_t x, y, z, w; };

__device__ __forceinline__ float bf2f(ushort_t u) {
  return __uint_as_float(((unsigned int)u) << 16);
}
__device__ __forceinline__ ushort_t f2bu(float f) {
  __hip_bfloat16 h = __float2bfloat16(f);
  return *reinterpret_cast<ushort_t*>(&h);
}

// ---------------- LayerNorm over channel dim ----------------
__global__ __launch_bounds__(256) void ln_ch(const float* __restrict__ x,
                                             const float* __restrict__ w,
                                             const float* __restrict__ b,
                                             float* __restrict__ out) {
  int p = blockIdx.x * 256 + threadIdx.x;  // over B*HW
  int bi = p >> 12;
  int pos = p & (HW_ - 1);
  const float* xb = x + (size_t)bi * C_ * HW_ + pos;
  float s = 0.f, ss = 0.f;
  for (int c = 0; c < C_; c++) {
    float v = xb[(size_t)c * HW_];
    s += v;
    ss = fmaf(v, v, ss);
  }
  float mu = s * (1.f / C_);
  float var = ss * (1.f / C_) - mu * mu;
  float inv = rsqrtf(var + 1e-5f);
  float* ob = out + (size_t)bi * C_ * HW_ + pos;
  for (int c = 0; c < C_; c++) {
    ob[(size_t)c * HW_] = (xb[(size_t)c * HW_] - mu) * inv * w[c] + b[c];
  }
}

// ---------------- vector load/store helpers ----------------
__device__ __forceinline__ void load4f(const float* p, float* v) {
  float4 t = *(const float4*)p;
  v[0] = t.x; v[1] = t.y; v[2] = t.z; v[3] = t.w;
}
__device__ __forceinline__ void load4f(const __hip_bfloat16* p, float* v) {
  us4 t = *(const us4*)p;
  v[0] = bf2f(t.x); v[1] = bf2f(t.y); v[2] = bf2f(t.z); v[3] = bf2f(t.w);
}
__device__ __forceinline__ void store4f(float* p, const float* v) {
  float4 t; t.x = v[0]; t.y = v[1]; t.z = v[2]; t.w = v[3];
  *(float4*)p = t;
}
__device__ __forceinline__ void store4f(__hip_bfloat16* p, const float* v) {
  us4 t; t.x = f2bu(v[0]); t.y = f2bu(v[1]); t.z = f2bu(v[2]); t.w = f2bu(v[3]);
  *(us4*)p = t;
}

// load 16-elem window rv[j] = row[cb-4+j], zero-padded outside [0,64)
__device__ __forceinline__ void loadrow_bf(const __hip_bfloat16* __restrict__ rowp,
                                           int cb, float* rv) {
#pragma unroll
  for (int b = 0; b < 4; b++) {
    int co = cb - 4 + b * 4;
    if ((unsigned)co <= 60u) {
      us4 t = *(const us4*)(rowp + co);
      rv[b * 4 + 0] = bf2f(t.x); rv[b * 4 + 1] = bf2f(t.y);
      rv[b * 4 + 2] = bf2f(t.z); rv[b * 4 + 3] = bf2f(t.w);
    } else {
      rv[b * 4 + 0] = 0.f; rv[b * 4 + 1] = 0.f;
      rv[b * 4 + 2] = 0.f; rv[b * 4 + 3] = 0.f;
    }
  }
}
__device__ __forceinline__ void loadrow_f(const float* __restrict__ rowp,
                                          int cb, float* rv) {
#pragma unroll
  for (int b = 0; b < 4; b++) {
    int co = cb - 4 + b * 4;
    if ((unsigned)co <= 60u) {
      float4 t = *(const float4*)(rowp + co);
      rv[b * 4 + 0] = t.x; rv[b * 4 + 1] = t.y;
      rv[b * 4 + 2] = t.z; rv[b * 4 + 3] = t.w;
    } else {
      rv[b * 4 + 0] = 0.f; rv[b * 4 + 1] = 0.f;
      rv[b * 4 + 2] = 0.f; rv[b * 4 + 3] = 0.f;
    }
  }
}

// ------- conv1x1 (GEMM over channels), 16 outputs x 4 positions, LDS weights -------
template <int CIN, typename Tin, typename Tout>
__global__ __launch_bounds__(256) void conv1x1_v(const Tin* __restrict__ in,
                                                 const float* __restrict__ wt,
                                                 const float* __restrict__ resid,
                                                 Tout* __restrict__ out,
                                                 int cout, int wstride, int accum) {
  __shared__ float wsh[CIN * 16];
  int tid = threadIdx.x;
  int blk = blockIdx.x;
  int pb = blk & 3;  // 4 position blocks of 1024
  int t = blk >> 2;
  int nob = cout >> 4;
  int ob = t % nob;
  int bi = t / nob;
  int pos = (pb << 10) + tid * 4;
  int o0 = ob << 4;
  for (int l = tid; l < CIN * 16; l += 256) {
    int c = l >> 4, j = l & 15;
    wsh[l] = wt[(size_t)(o0 + j) * wstride + c];
  }
  __syncthreads();

  const Tin* ib = in + (size_t)bi * CIN * HW_ + pos;
  float acc[16][4] = {};
#pragma unroll 4
  for (int c = 0; c < CIN; c++) {
    float xv[4];
    load4f(ib + (size_t)c * HW_, xv);
    const float* wr = &wsh[c * 16];
#pragma unroll
    for (int j = 0; j < 16; j++) {
      float wv = wr[j];
      acc[j][0] = fmaf(wv, xv[0], acc[j][0]);
      acc[j][1] = fmaf(wv, xv[1], acc[j][1]);
      acc[j][2] = fmaf(wv, xv[2], acc[j][2]);
      acc[j][3] = fmaf(wv, xv[3], acc[j][3]);
    }
  }
  Tout* op = out + ((size_t)bi * cout + o0) * HW_ + pos;
  const float* rp = resid ? resid + ((size_t)bi * cout + o0) * HW_ + pos : nullptr;
#pragma unroll
  for (int j = 0; j < 16; j++) {
    float v[4];
    v[0] = acc[j][0]; v[1] = acc[j][1]; v[2] = acc[j][2]; v[3] = acc[j][3];
    if (rp) {
      float rv[4];
      load4f(rp + (size_t)j * HW_, rv);
      for (int q = 0; q < 4; q++) v[q] += rv[q];
    }
    if (accum) {
      float ov[4];
      load4f(op + (size_t)j * HW_, ov);
      for (int q = 0; q < 4; q++) v[q] += ov[q];
    }
    store4f(op + (size_t)j * HW_, v);
  }
}

// ------- depthwise conv, direct-global vectorized windows, 8 out/thread -------
// No image LDS: 4 predicated float4 loads per tap-row (L1-resident), all indices
// compile-time. Small live set -> VGPR <= 128 quantum (R8 post-mortem).
template <int K>
__global__ __launch_bounds__(256) void dwconv_d(const float* __restrict__ q0,
                                                const float* __restrict__ k0,
                                                const float* __restrict__ v0,
                                                const float* __restrict__ wq_,
                                                const float* __restrict__ wk_,
                                                const float* __restrict__ wv_,
                                                float* __restrict__ qd,
                                                float* __restrict__ kd,
                                                float* __restrict__ vd) {
  constexpr int P = K / 2;
  __shared__ float wsh[K * K];
  int sel = blockIdx.y;
  const float* in = (sel == 0) ? q0 : (sel == 1) ? k0 : v0;
  const float* wgt = (sel == 0) ? wq_ : (sel == 1) ? wk_ : wv_;
  float* outp = (sel == 0) ? qd : (sel == 1) ? kd : vd;
  int blk = blockIdx.x;  // B*C*2
  int half = blk & 1;
  int c = (blk >> 1) & (C_ - 1);
  int bi = blk >> 8;
  int tid = threadIdx.x;

  if (tid < K * K) wsh[tid] = wgt[(size_t)c * K * K + tid];
  __syncthreads();

  int r = tid >> 3;
  int cb = (tid & 7) << 3;
  int y = half * 32 + r;
  const float* plane = in + (size_t)(bi * C_ + c) * HW_;

  float a[8];
#pragma unroll
  for (int o = 0; o < 8; o++) a[o] = 0.f;
#pragma unroll
  for (int dy = 0; dy < K; dy++) {
    int gy = y + dy - P;
    if ((unsigned)gy < 64u) {
      float rv[16];
      loadrow_f(plane + gy * 64, cb, rv);
#pragma unroll
      for (int dx = 0; dx < K; dx++) {
        float wv = wsh[dy * K + dx];
#pragma unroll
        for (int o = 0; o < 8; o++) a[o] = fmaf(rv[o + dx + 4 - P], wv, a[o]);
      }
    }
  }
  float* ob = outp + (size_t)(bi * C_ + c) * HW_ + y * 64 + cb;
  store4f(ob, &a[0]);
  store4f(ob + 4, &a[4]);
}

// ------- FFN depthwise conv + GEGLU gate, direct-global, 8 out/thread -------
template <int K>
__global__ __launch_bounds__(256) void ffn_dwgate_d(const __hip_bfloat16* __restrict__ xin,
                                                    const float* __restrict__ w,
                                                    __hip_bfloat16* __restrict__ gated) {
  constexpr int P = K / 2;
  __shared__ float wsh[2 * K * K];
  int blk = blockIdx.x;  // B*512*2
  int half = blk & 1;
  int i = (blk >> 1) & 511;
  int bi = blk >> 10;
  int tid = threadIdx.x;

  if (tid < 2 * K * K) {
    wsh[tid] = (tid < K * K) ? w[(size_t)i * K * K + tid]
                             : w[(size_t)(512 + i) * K * K + (tid - K * K)];
  }
  __syncthreads();

  int r = tid >> 3;
  int cb = (tid & 7) << 3;
  int y = half * 32 + r;
  const __hip_bfloat16* gin = xin + (size_t)(bi * 1024 + i) * HW_;
  const __hip_bfloat16* min_ = gin + (size_t)512 * HW_;

  // ---- gate plane ----
  float ge[8];
  {
    float a[8];
#pragma unroll
    for (int o = 0; o < 8; o++) a[o] = 0.f;
#pragma unroll
    for (int dy = 0; dy < K; dy++) {
      int gy = y + dy - P;
      if ((unsigned)gy < 64u) {
        float rv[16];
        loadrow_bf(gin + gy * 64, cb, rv);
#pragma unroll
        for (int dx = 0; dx < K; dx++) {
          float wv = wsh[dy * K + dx];
#pragma unroll
          for (int o = 0; o < 8; o++) a[o] = fmaf(rv[o + dx + 4 - P], wv, a[o]);
        }
      }
    }
#pragma unroll
    for (int o = 0; o < 8; o++)
      ge[o] = 0.5f * a[o] * (1.f + erff(a[o] * 0.70710678118654752f));
  }

  // ---- mult plane ----
  float ma[8];
#pragma unroll
  for (int o = 0; o < 8; o++) ma[o] = 0.f;
#pragma unroll
  for (int dy = 0; dy < K; dy++) {
    int gy = y + dy - P;
    if ((unsigned)gy < 64u) {
      float rv[16];
      loadrow_bf(min_ + gy * 64, cb, rv);
#pragma unroll
      for (int dx = 0; dx < K; dx++) {
        float wv = wsh[K * K + dy * K + dx];
#pragma unroll
        for (int o = 0; o < 8; o++) ma[o] = fmaf(rv[o + dx + 4 - P], wv, ma[o]);
      }
    }
  }
  __hip_bfloat16* gp = gated + (size_t)(bi * 512 + i) * HW_ + y * 64 + cb;
#pragma unroll
  for (int v = 0; v < 2; v++) {
    us4 t;
    t.x = f2bu(ge[v * 4 + 0] * ma[v * 4 + 0]);
    t.y = f2bu(ge[v * 4 + 1] * ma[v * 4 + 1]);
    t.z = f2bu(ge[v * 4 + 2] * ma[v * 4 + 2]);
    t.w = f2bu(ge[v * 4 + 3] * ma[v * 4 + 3]);
    *(us4*)(gp + v * 4) = t;
  }
}

// ---------------- inverse L2 norms of qd and kd rows ----------------
__global__ __launch_bounds__(256) void l2_invnorm(const float* __restrict__ qd,
                                                  const float* __restrict__ kd,
                                                  float* __restrict__ invn) {
  int row = blockIdx.x;  // 0..2047; <1024 -> qd, else kd
  const float* src = (row < 1024) ? (qd + (size_t)row * HW_)
                                  : (kd + (size_t)(row - 1024) * HW_);
  float s = 0.f;
  for (int n = threadIdx.x; n < HW_; n += 256) {
    float v = src[n];
    s = fmaf(v, v, s);
  }
#pragma unroll
  for (int o = 32; o >= 1; o >>= 1) s += __shfl_xor(s, o, 64);
  __shared__ float red[4];
  if ((threadIdx.x & 63) == 0) red[threadIdx.x >> 6] = s;
  __syncthreads();
  if (threadIdx.x == 0) {
    float t = red[0] + red[1] + red[2] + red[3];
    invn[row] = 1.f / fmaxf(sqrtf(t), 1e-12f);
  }
}

// ---------------- attention: partial scores over 256-position chunks ----------------
__global__ __launch_bounds__(256) void attn_score_part(const float* __restrict__ qd,
                                                       const float* __restrict__ kd,
                                                       float* __restrict__ part) {
  constexpr int ST = 258;
  __shared__ float qs[16 * ST];
  __shared__ float ks[16 * ST];
  int bh = blockIdx.x;   // 64
  int ch = blockIdx.y;   // 16 chunks of 256
  int bi = bh >> 3;
  int h = bh & 7;
  int tid = threadIdx.x;
  int c = tid >> 4;
  int d = tid & 15;

  const float* qrow = qd + (size_t)(bi * C_ + h * CH_) * HW_ + ch * 256;
  const float* krow = kd + (size_t)(bi * C_ + h * CH_) * HW_ + ch * 256;
#pragma unroll
  for (int it = 0; it < 4; it++) {
    int idx = tid + it * 256;
    int r = idx >> 6, q4 = idx & 63;
    float4 qv = ((const float4*)(qrow + (size_t)r * HW_))[q4];
    float4 kv = ((const float4*)(krow + (size_t)r * HW_))[q4];
    float* qdst = &qs[r * ST + q4 * 4];
    float* kdst = &ks[r * ST + q4 * 4];
    qdst[0] = qv.x; qdst[1] = qv.y; qdst[2] = qv.z; qdst[3] = qv.w;
    kdst[0] = kv.x; kdst[1] = kv.y; kdst[2] = kv.z; kdst[3] = kv.w;
  }
  __syncthreads();

  const float* qp = &qs[c * ST];
  const float* kp = &ks[d * ST];
  float acc = 0.f;
#pragma unroll 8
  for (int j = 0; j < 256; j++) acc = fmaf(qp[j], kp[j], acc);
  part[((size_t)bh * 16 + ch) * 256 + tid] = acc;
}

// ---------------- attention: reduce partials + softmax ----------------
__global__ __launch_bounds__(256) void attn_softmax(const float* __restrict__ part,
                                                    const float* __restrict__ invn,
                                                    const float* __restrict__ temp,
                                                    float* __restrict__ as_buf) {
  int bh = blockIdx.x;  // 64
  int bi = bh >> 3;
  int h = bh & 7;
  int tid = threadIdx.x;
  int c = tid >> 4;
  int d = tid & 15;
  float s = 0.f;
  const float* pp = part + (size_t)bh * 16 * 256 + tid;
#pragma unroll
  for (int ch = 0; ch < 16; ch++) s += pp[ch * 256];
  float S = s * invn[bi * C_ + h * CH_ + c] * invn[1024 + bi * C_ + h * CH_ + d] *
            temp[h];
  float mx = S;
#pragma unroll
  for (int o = 8; o >= 1; o >>= 1) mx = fmaxf(mx, __shfl_xor(mx, o, 16));
  float e = expf(S - mx);
  float sm = e;
#pragma unroll
  for (int o = 8; o >= 1; o >>= 1) sm += __shfl_xor(sm, o, 16);
  as_buf[(size_t)bh * 256 + tid] = e / sm;
}

// ---------------- attention: PV over 256-position chunks ----------------
__global__ __launch_bounds__(256) void attn_pv(const float* __restrict__ vd,
                                               const float* __restrict__ as_buf,
                                               float* __restrict__ osb) {
  __shared__ float as[16][17];
  int bh = blockIdx.x;  // 64
  int ch = blockIdx.y;  // 16
  int bi = bh >> 3;
  int h = bh & 7;
  int tid = threadIdx.x;
  if (tid < 256) {
    int cc = tid >> 4, dd = tid & 15;
    as[cc][dd] = as_buf[(size_t)bh * 256 + tid];
  }
  __syncthreads();

  int n = ch * 256 + tid;
  const float* vrow = vd + (size_t)(bi * C_ + h * CH_) * HW_ + n;
  float o_[16];
#pragma unroll
  for (int cc = 0; cc < 16; cc++) o_[cc] = 0.f;
#pragma unroll
  for (int dd = 0; dd < 16; dd++) {
    float vv = vrow[(size_t)dd * HW_];
#pragma unroll
    for (int cc = 0; cc < 16; cc++) o_[cc] = fmaf(as[cc][dd], vv, o_[cc]);
  }
  float* ob = osb + (size_t)(bi * C_ + h * CH_) * HW_ + n;
#pragma unroll
  for (int cc = 0; cc < 16; cc++) ob[(size_t)cc * HW_] = o_[cc];
}

extern "C" void kernel_launch(void* const* d_in, const int* in_sizes, int n_in,
                              void* d_out, int out_size, void* d_ws, size_t ws_size,
                              hipStream_t stream) {
  const float* x = (const float*)d_in[0];
  const float* ln1_w = (const float*)d_in[1];
  const float* ln1_b = (const float*)d_in[2];
  const float* temp = (const float*)d_in[3];
  const float* wq = (const float*)d_in[4];
  const float* wk = (const float*)d_in[5];
  const float* wv = (const float*)d_in[6];
  const float* dw[9];
  for (int i = 0; i < 9; i++) dw[i] = (const float*)d_in[7 + i];
  const float* attn_po = (const float*)d_in[16];
  const float* ln2_w = (const float*)d_in[17];
  const float* ln2_b = (const float*)d_in[18];
  const float* ffn_in = (const float*)d_in[19];
  const float* ffn_dw[3] = {(const float*)d_in[20], (const float*)d_in[21],
                            (const float*)d_in[22]};
  const float* ffn_po = (const float*)d_in[23];
  float* out = (float*)d_out;

  // ---- workspace layout: peak 128 MiB + 72 KiB, lifetime-aliased ----
  const size_t MB = (size_t)1 << 20;
  char* wsb = (char*)d_ws;
  float* xn = (float*)(wsb + 0 * MB);
  float* q0 = (float*)(wsb + 16 * MB);
  float* k0 = (float*)(wsb + 32 * MB);
  float* v0 = (float*)(wsb + 48 * MB);
  float* qd = (float*)(wsb + 64 * MB);
  float* kd = (float*)(wsb + 80 * MB);
  float* vd = (float*)(wsb + 96 * MB);
  float* x2 = (float*)(wsb + 112 * MB);
  float* invn = (float*)(wsb + 128 * MB);               // 8 KiB
  float* as_buf = (float*)(wsb + 128 * MB + 8 * 1024);  // 64 KiB
  float* osb = xn;
  float* xn2 = xn;
  float* part = xn;  // 4 MB partial-score buffer; dead before osb is written
  __hip_bfloat16* xin = (__hip_bfloat16*)(wsb + 16 * MB);    // 64 MB
  __hip_bfloat16* gated = (__hip_bfloat16*)(wsb + 80 * MB);  // 32 MB

  const int ln_grid = (B_ * HW_) / 256;                  // 128
  const int c128_grid = B_ * (C_ / 16) * 4;              // 256
  const int c1024_grid = B_ * (1024 / 16) * 4;           // 2048
  const dim3 dwt_grid(B_ * C_ * 2, 3);                   // 2048 x 3
  const int ffg_grid = B_ * 512 * 2;                     // 8192
  const dim3 att_grid(B_ * HEADS_, 16);                  // 64 x 16

  // ---- attention branch ----
  ln_ch<<<ln_grid, 256, 0, stream>>>(x, ln1_w, ln1_b, xn);
  conv1x1_v<C_, float, float><<<c128_grid, 256, 0, stream>>>(xn, wq, nullptr, q0, C_, C_, 0);
  conv1x1_v<C_, float, float><<<c128_grid, 256, 0, stream>>>(xn, wk, nullptr, k0, C_, C_, 0);
  conv1x1_v<C_, float, float><<<c128_grid, 256, 0, stream>>>(xn, wv, nullptr, v0, C_, C_, 0);

  for (int s = 0; s < 3; s++) {
    if (s == 0)
      dwconv_d<3><<<dwt_grid, 256, 0, stream>>>(q0, k0, v0, dw[0], dw[1], dw[2], qd, kd, vd);
    else if (s == 1)
      dwconv_d<5><<<dwt_grid, 256, 0, stream>>>(q0, k0, v0, dw[3], dw[4], dw[5], qd, kd, vd);
    else
      dwconv_d<7><<<dwt_grid, 256, 0, stream>>>(q0, k0, v0, dw[6], dw[7], dw[8], qd, kd, vd);
    l2_invnorm<<<2048, 256, 0, stream>>>(qd, kd, invn);
    attn_score_part<<<att_grid, 256, 0, stream>>>(qd, kd, part);
    attn_softmax<<<B_ * HEADS_, 256, 0, stream>>>(part, invn, temp, as_buf);
    attn_pv<<<att_grid, 256, 0, stream>>>(vd, as_buf, osb);
    conv1x1_v<C_, float, float><<<c128_grid, 256, 0, stream>>>(
        osb, attn_po + s * C_, (s == 0) ? x : nullptr, x2, C_, 3 * C_, s == 0 ? 0 : 1);
  }

  // ---- FFN branch ----
  ln_ch<<<ln_grid, 256, 0, stream>>>(x2, ln2_w, ln2_b, xn2);
  conv1x1_v<C_, float, __hip_bfloat16><<<c1024_grid, 256, 0, stream>>>(
      xn2, ffn_in, nullptr, xin, 1024, C_, 0);

  for (int s = 0; s < 3; s++) {
    if (s == 0)
      ffn_dwgate_d<3><<<ffg_grid, 256, 0, stream>>>(xin, ffn_dw[0], gated);
    else if (s == 1)
      ffn_dwgate_d<5><<<ffg_grid, 256, 0, stream>>>(xin, ffn_dw[1], gated);
    else
      ffn_dwgate_d<7><<<ffg_grid, 256, 0, stream>>>(xin, ffn_dw[2], gated);
    conv1x1_v<512, __hip_bfloat16, float><<<c128_grid, 256, 0, stream>>>(
        gated, ffn_po + s * 512, (s == 0) ? x2 : nullptr, out, C_, 3 * HID_,
        s == 0 ? 0 : 1);
  }
  (void)in_sizes; (void)n_in; (void)out_size; (void)ws_size;
}

// Round 10
// 602.349 us; speedup vs baseline: 2.0454x; 1.8662x over previous
//
#include <hip/hip_runtime.h>
#include <hip/hip_bf16.h>
#include <math.h>

#define B_ 8
#define C_ 128
#define H_ 64
#define W_ 64
#define HW_ 4096
#define HEADS_ 8
#define CH_ 16
#define HID_ 512

typedef unsigned short ushort_t;
struct __attribute__((aligned(8))) us4 { ushort_t x, y, z, w; };

typedef __attribute__((ext_vector_type(8))) short bf16x8;
typedef __attribute__((ext_vector_type(4))) float f32x4;

__device__ __forceinline__ float bf2f(ushort_t u) {
  return __uint_as_float(((unsigned int)u) << 16);
}
__device__ __forceinline__ ushort_t f2bu(float f) {
  __hip_bfloat16 h = __float2bfloat16(f);
  return *reinterpret_cast<ushort_t*>(&h);
}
__device__ __forceinline__ float toF(float v) { return v; }
__device__ __forceinline__ float toF(__hip_bfloat16 v) { return __bfloat162float(v); }
__device__ __forceinline__ void storeF(float* p, float v) { *p = v; }
__device__ __forceinline__ void storeF(__hip_bfloat16* p, float v) { *p = __float2bfloat16(v); }

// ---------------- LayerNorm over channel dim ----------------
__global__ __launch_bounds__(256) void ln_ch(const float* __restrict__ x,
                                             const float* __restrict__ w,
                                             const float* __restrict__ b,
                                             float* __restrict__ out) {
  int p = blockIdx.x * 256 + threadIdx.x;  // over B*HW
  int bi = p >> 12;
  int pos = p & (HW_ - 1);
  const float* xb = x + (size_t)bi * C_ * HW_ + pos;
  float s = 0.f, ss = 0.f;
  for (int c = 0; c < C_; c++) {
    float v = xb[(size_t)c * HW_];
    s += v;
    ss = fmaf(v, v, ss);
  }
  float mu = s * (1.f / C_);
  float var = ss * (1.f / C_) - mu * mu;
  float inv = rsqrtf(var + 1e-5f);
  float* ob = out + (size_t)bi * C_ * HW_ + pos;
  for (int c = 0; c < C_; c++) {
    ob[(size_t)c * HW_] = (xb[(size_t)c * HW_] - mu) * inv * w[c] + b[c];
  }
}

// ---------------- vector load/store helpers ----------------
__device__ __forceinline__ void load4f(const float* p, float* v) {
  float4 t = *(const float4*)p;
  v[0] = t.x; v[1] = t.y; v[2] = t.z; v[3] = t.w;
}
__device__ __forceinline__ void load4f(const __hip_bfloat16* p, float* v) {
  us4 t = *(const us4*)p;
  v[0] = bf2f(t.x); v[1] = bf2f(t.y); v[2] = bf2f(t.z); v[3] = bf2f(t.w);
}
__device__ __forceinline__ void store4f(float* p, const float* v) {
  float4 t; t.x = v[0]; t.y = v[1]; t.z = v[2]; t.w = v[3];
  *(float4*)p = t;
}
__device__ __forceinline__ void store4f(__hip_bfloat16* p, const float* v) {
  us4 t; t.x = f2bu(v[0]); t.y = f2bu(v[1]); t.z = f2bu(v[2]); t.w = f2bu(v[3]);
  *(us4*)p = t;
}

// load 16-elem window rv[j] = row[cb-4+j], zero-padded outside [0,64)
__device__ __forceinline__ void loadrow_bf(const __hip_bfloat16* __restrict__ rowp,
                                           int cb, float* rv) {
#pragma unroll
  for (int b = 0; b < 4; b++) {
    int co = cb - 4 + b * 4;
    if ((unsigned)co <= 60u) {
      us4 t = *(const us4*)(rowp + co);
      rv[b * 4 + 0] = bf2f(t.x); rv[b * 4 + 1] = bf2f(t.y);
      rv[b * 4 + 2] = bf2f(t.z); rv[b * 4 + 3] = bf2f(t.w);
    } else {
      rv[b * 4 + 0] = 0.f; rv[b * 4 + 1] = 0.f;
      rv[b * 4 + 2] = 0.f; rv[b * 4 + 3] = 0.f;
    }
  }
}
__device__ __forceinline__ void loadrow_f(const float* __restrict__ rowp,
                                          int cb, float* rv) {
#pragma unroll
  for (int b = 0; b < 4; b++) {
    int co = cb - 4 + b * 4;
    if ((unsigned)co <= 60u) {
      float4 t = *(const float4*)(rowp + co);
      rv[b * 4 + 0] = t.x; rv[b * 4 + 1] = t.y;
      rv[b * 4 + 2] = t.z; rv[b * 4 + 3] = t.w;
    } else {
      rv[b * 4 + 0] = 0.f; rv[b * 4 + 1] = 0.f;
      rv[b * 4 + 2] = 0.f; rv[b * 4 + 3] = 0.f;
    }
  }
}

// ------- conv1x1 as bf16 MFMA GEMM: Out[cout][HW] = W[cout][cin] @ In[cin][HW] -------
// Per block (256 thr = 4 waves): 64(M) x 64(N) tile. mfma_f32_16x16x32_bf16.
// Fragment layouts (verified m89/m92): A/B lane holds 8 contiguous K at k0=8*(lane>>4),
// row/col = lane&15; C/D col=lane&15, row=4*(lane>>4)+reg.
template <typename Tin, typename Tout>
__global__ __launch_bounds__(256) void conv1x1_m(const Tin* __restrict__ in,
                                                 const float* __restrict__ wt,
                                                 const float* __restrict__ resid,
                                                 Tout* __restrict__ out,
                                                 int cin, int cout, int wstride,
                                                 int accum) {
  constexpr int ST = 68;  // LDS row stride (bf16 elems): writes conflict-free, col-reads <=4-way
  __shared__ ushort_t bsh[128 * ST];
  int tid = threadIdx.x;
  int lane = tid & 63;
  int wv = tid >> 6;
  int lrow = lane & 15;
  int lk = lane >> 4;
  int blk = blockIdx.x;
  int nb = blk & 63;
  int rest = blk >> 6;
  int mb = cout >> 6;
  int m = rest % mb;
  int bi = rest / mb;
  int n0 = nb << 6;
  int o0 = (m << 6) + wv * 16;

  f32x4 acc[4] = {{0.f, 0.f, 0.f, 0.f}, {0.f, 0.f, 0.f, 0.f},
                  {0.f, 0.f, 0.f, 0.f}, {0.f, 0.f, 0.f, 0.f}};

  int cl = tid >> 4;  // 0..15 staging row group
  int j4 = tid & 15;  // staging col quad
  for (int kc = 0; kc < cin; kc += 128) {
    // ---- stage In[kc+c][n0..n0+63] -> bf16 LDS tile [128][ST] ----
#pragma unroll
    for (int p = 0; p < 8; p++) {
      int c = p * 16 + cl;
      const Tin* src = in + ((size_t)bi * cin + kc + c) * HW_ + n0 + j4 * 4;
      us4 u;
      if constexpr (sizeof(Tin) == 4) {
        float4 v = *(const float4*)src;
        u.x = f2bu(v.x); u.y = f2bu(v.y); u.z = f2bu(v.z); u.w = f2bu(v.w);
      } else {
        u = *(const us4*)src;
      }
      *(us4*)&bsh[c * ST + j4 * 4] = u;
    }
    __syncthreads();
    // ---- 4 K-steps of 32 ----
#pragma unroll
    for (int ks = 0; ks < 4; ks++) {
      const float* wr = wt + (size_t)(o0 + lrow) * wstride + kc + ks * 32 + lk * 8;
      float4 wa = *(const float4*)wr;
      float4 wb2 = *(const float4*)(wr + 4);
      bf16x8 af;
      af[0] = (short)f2bu(wa.x); af[1] = (short)f2bu(wa.y);
      af[2] = (short)f2bu(wa.z); af[3] = (short)f2bu(wa.w);
      af[4] = (short)f2bu(wb2.x); af[5] = (short)f2bu(wb2.y);
      af[6] = (short)f2bu(wb2.z); af[7] = (short)f2bu(wb2.w);
#pragma unroll
      for (int s = 0; s < 4; s++) {
        int rb = (ks * 32 + lk * 8) * ST + s * 16 + lrow;
        bf16x8 bf_;
#pragma unroll
        for (int j = 0; j < 8; j++) bf_[j] = (short)bsh[rb + j * ST];
        acc[s] = __builtin_amdgcn_mfma_f32_16x16x32_bf16(af, bf_, acc[s], 0, 0, 0);
      }
    }
    __syncthreads();
  }

  // ---- epilogue: D[o][n], o = o0+4*lk+r, n = n0+s*16+lrow ----
  const float* rp = resid ? resid + (size_t)bi * cout * HW_ : nullptr;
  Tout* op = out + (size_t)bi * cout * HW_;
#pragma unroll
  for (int s = 0; s < 4; s++) {
#pragma unroll
    for (int r = 0; r < 4; r++) {
      int o = o0 + lk * 4 + r;
      int n = n0 + s * 16 + lrow;
      size_t off = (size_t)o * HW_ + n;
      float v = acc[s][r];
      if (rp) v += rp[off];
      if (accum) v += toF(op[off]);
      storeF(&op[off], v);
    }
  }
}

// ------- depthwise conv, direct-global vectorized windows, 8 out/thread -------
template <int K>
__global__ __launch_bounds__(256) void dwconv_d(const float* __restrict__ q0,
                                                const float* __restrict__ k0,
                                                const float* __restrict__ v0,
                                                const float* __restrict__ wq_,
                                                const float* __restrict__ wk_,
                                                const float* __restrict__ wv_,
                                                float* __restrict__ qd,
                                                float* __restrict__ kd,
                                                float* __restrict__ vd) {
  constexpr int P = K / 2;
  __shared__ float wsh[K * K];
  int sel = blockIdx.y;
  const float* in = (sel == 0) ? q0 : (sel == 1) ? k0 : v0;
  const float* wgt = (sel == 0) ? wq_ : (sel == 1) ? wk_ : wv_;
  float* outp = (sel == 0) ? qd : (sel == 1) ? kd : vd;
  int blk = blockIdx.x;  // B*C*2
  int half = blk & 1;
  int c = (blk >> 1) & (C_ - 1);
  int bi = blk >> 8;
  int tid = threadIdx.x;

  if (tid < K * K) wsh[tid] = wgt[(size_t)c * K * K + tid];
  __syncthreads();

  int r = tid >> 3;
  int cb = (tid & 7) << 3;
  int y = half * 32 + r;
  const float* plane = in + (size_t)(bi * C_ + c) * HW_;

  float a[8];
#pragma unroll
  for (int o = 0; o < 8; o++) a[o] = 0.f;
#pragma unroll
  for (int dy = 0; dy < K; dy++) {
    int gy = y + dy - P;
    if ((unsigned)gy < 64u) {
      float rv[16];
      loadrow_f(plane + gy * 64, cb, rv);
#pragma unroll
      for (int dx = 0; dx < K; dx++) {
        float wv = wsh[dy * K + dx];
#pragma unroll
        for (int o = 0; o < 8; o++) a[o] = fmaf(rv[o + dx + 4 - P], wv, a[o]);
      }
    }
  }
  float* ob = outp + (size_t)(bi * C_ + c) * HW_ + y * 64 + cb;
  store4f(ob, &a[0]);
  store4f(ob + 4, &a[4]);
}

// ------- FFN depthwise conv + GEGLU gate, direct-global, 8 out/thread -------
template <int K>
__global__ __launch_bounds__(256) void ffn_dwgate_d(const __hip_bfloat16* __restrict__ xin,
                                                    const float* __restrict__ w,
                                                    __hip_bfloat16* __restrict__ gated) {
  constexpr int P = K / 2;
  __shared__ float wsh[2 * K * K];
  int blk = blockIdx.x;  // B*512*2
  int half = blk & 1;
  int i = (blk >> 1) & 511;
  int bi = blk >> 10;
  int tid = threadIdx.x;

  if (tid < 2 * K * K) {
    wsh[tid] = (tid < K * K) ? w[(size_t)i * K * K + tid]
                             : w[(size_t)(512 + i) * K * K + (tid - K * K)];
  }
  __syncthreads();

  int r = tid >> 3;
  int cb = (tid & 7) << 3;
  int y = half * 32 + r;
  const __hip_bfloat16* gin = xin + (size_t)(bi * 1024 + i) * HW_;
  const __hip_bfloat16* min_ = gin + (size_t)512 * HW_;

  // ---- gate plane ----
  float ge[8];
  {
    float a[8];
#pragma unroll
    for (int o = 0; o < 8; o++) a[o] = 0.f;
#pragma unroll
    for (int dy = 0; dy < K; dy++) {
      int gy = y + dy - P;
      if ((unsigned)gy < 64u) {
        float rv[16];
        loadrow_bf(gin + gy * 64, cb, rv);
#pragma unroll
        for (int dx = 0; dx < K; dx++) {
          float wv = wsh[dy * K + dx];
#pragma unroll
          for (int o = 0; o < 8; o++) a[o] = fmaf(rv[o + dx + 4 - P], wv, a[o]);
        }
      }
    }
#pragma unroll
    for (int o = 0; o < 8; o++)
      ge[o] = 0.5f * a[o] * (1.f + erff(a[o] * 0.70710678118654752f));
  }

  // ---- mult plane ----
  float ma[8];
#pragma unroll
  for (int o = 0; o < 8; o++) ma[o] = 0.f;
#pragma unroll
  for (int dy = 0; dy < K; dy++) {
    int gy = y + dy - P;
    if ((unsigned)gy < 64u) {
      float rv[16];
      loadrow_bf(min_ + gy * 64, cb, rv);
#pragma unroll
      for (int dx = 0; dx < K; dx++) {
        float wv = wsh[K * K + dy * K + dx];
#pragma unroll
        for (int o = 0; o < 8; o++) ma[o] = fmaf(rv[o + dx + 4 - P], wv, ma[o]);
      }
    }
  }
  __hip_bfloat16* gp = gated + (size_t)(bi * 512 + i) * HW_ + y * 64 + cb;
#pragma unroll
  for (int v = 0; v < 2; v++) {
    us4 t;
    t.x = f2bu(ge[v * 4 + 0] * ma[v * 4 + 0]);
    t.y = f2bu(ge[v * 4 + 1] * ma[v * 4 + 1]);
    t.z = f2bu(ge[v * 4 + 2] * ma[v * 4 + 2]);
    t.w = f2bu(ge[v * 4 + 3] * ma[v * 4 + 3]);
    *(us4*)(gp + v * 4) = t;
  }
}

// ---------------- inverse L2 norms of qd and kd rows ----------------
__global__ __launch_bounds__(256) void l2_invnorm(const float* __restrict__ qd,
                                                  const float* __restrict__ kd,
                                                  float* __restrict__ invn) {
  int row = blockIdx.x;  // 0..2047; <1024 -> qd, else kd
  const float* src = (row < 1024) ? (qd + (size_t)row * HW_)
                                  : (kd + (size_t)(row - 1024) * HW_);
  float s = 0.f;
  for (int n = threadIdx.x; n < HW_; n += 256) {
    float v = src[n];
    s = fmaf(v, v, s);
  }
#pragma unroll
  for (int o = 32; o >= 1; o >>= 1) s += __shfl_xor(s, o, 64);
  __shared__ float red[4];
  if ((threadIdx.x & 63) == 0) red[threadIdx.x >> 6] = s;
  __syncthreads();
  if (threadIdx.x == 0) {
    float t = red[0] + red[1] + red[2] + red[3];
    invn[row] = 1.f / fmaxf(sqrtf(t), 1e-12f);
  }
}

// ---------------- attention: partial scores over 256-position chunks ----------------
__global__ __launch_bounds__(256) void attn_score_part(const float* __restrict__ qd,
                                                       const float* __restrict__ kd,
                                                       float* __restrict__ part) {
  constexpr int ST = 258;
  __shared__ float qs[16 * ST];
  __shared__ float ks[16 * ST];
  int bh = blockIdx.x;   // 64
  int ch = blockIdx.y;   // 16 chunks of 256
  int bi = bh >> 3;
  int h = bh & 7;
  int tid = threadIdx.x;
  int c = tid >> 4;
  int d = tid & 15;

  const float* qrow = qd + (size_t)(bi * C_ + h * CH_) * HW_ + ch * 256;
  const float* krow = kd + (size_t)(bi * C_ + h * CH_) * HW_ + ch * 256;
#pragma unroll
  for (int it = 0; it < 4; it++) {
    int idx = tid + it * 256;
    int r = idx >> 6, q4 = idx & 63;
    float4 qv = ((const float4*)(qrow + (size_t)r * HW_))[q4];
    float4 kv = ((const float4*)(krow + (size_t)r * HW_))[q4];
    float* qdst = &qs[r * ST + q4 * 4];
    float* kdst = &ks[r * ST + q4 * 4];
    qdst[0] = qv.x; qdst[1] = qv.y; qdst[2] = qv.z; qdst[3] = qv.w;
    kdst[0] = kv.x; kdst[1] = kv.y; kdst[2] = kv.z; kdst[3] = kv.w;
  }
  __syncthreads();

  const float* qp = &qs[c * ST];
  const float* kp = &ks[d * ST];
  float acc = 0.f;
#pragma unroll 8
  for (int j = 0; j < 256; j++) acc = fmaf(qp[j], kp[j], acc);
  part[((size_t)bh * 16 + ch) * 256 + tid] = acc;
}

// ---------------- attention: reduce partials + softmax ----------------
__global__ __launch_bounds__(256) void attn_softmax(const float* __restrict__ part,
                                                    const float* __restrict__ invn,
                                                    const float* __restrict__ temp,
                                                    float* __restrict__ as_buf) {
  int bh = blockIdx.x;  // 64
  int bi = bh >> 3;
  int h = bh & 7;
  int tid = threadIdx.x;
  int c = tid >> 4;
  int d = tid & 15;
  float s = 0.f;
  const float* pp = part + (size_t)bh * 16 * 256 + tid;
#pragma unroll
  for (int ch = 0; ch < 16; ch++) s += pp[ch * 256];
  float S = s * invn[bi * C_ + h * CH_ + c] * invn[1024 + bi * C_ + h * CH_ + d] *
            temp[h];
  float mx = S;
#pragma unroll
  for (int o = 8; o >= 1; o >>= 1) mx = fmaxf(mx, __shfl_xor(mx, o, 16));
  float e = expf(S - mx);
  float sm = e;
#pragma unroll
  for (int o = 8; o >= 1; o >>= 1) sm += __shfl_xor(sm, o, 16);
  as_buf[(size_t)bh * 256 + tid] = e / sm;
}

// ---------------- attention: PV over 256-position chunks ----------------
__global__ __launch_bounds__(256) void attn_pv(const float* __restrict__ vd,
                                               const float* __restrict__ as_buf,
                                               float* __restrict__ osb) {
  __shared__ float as[16][17];
  int bh = blockIdx.x;  // 64
  int ch = blockIdx.y;  // 16
  int bi = bh >> 3;
  int h = bh & 7;
  int tid = threadIdx.x;
  if (tid < 256) {
    int cc = tid >> 4, dd = tid & 15;
    as[cc][dd] = as_buf[(size_t)bh * 256 + tid];
  }
  __syncthreads();

  int n = ch * 256 + tid;
  const float* vrow = vd + (size_t)(bi * C_ + h * CH_) * HW_ + n;
  float o_[16];
#pragma unroll
  for (int cc = 0; cc < 16; cc++) o_[cc] = 0.f;
#pragma unroll
  for (int dd = 0; dd < 16; dd++) {
    float vv = vrow[(size_t)dd * HW_];
#pragma unroll
    for (int cc = 0; cc < 16; cc++) o_[cc] = fmaf(as[cc][dd], vv, o_[cc]);
  }
  float* ob = osb + (size_t)(bi * C_ + h * CH_) * HW_ + n;
#pragma unroll
  for (int cc = 0; cc < 16; cc++) ob[(size_t)cc * HW_] = o_[cc];
}

extern "C" void kernel_launch(void* const* d_in, const int* in_sizes, int n_in,
                              void* d_out, int out_size, void* d_ws, size_t ws_size,
                              hipStream_t stream) {
  const float* x = (const float*)d_in[0];
  const float* ln1_w = (const float*)d_in[1];
  const float* ln1_b = (const float*)d_in[2];
  const float* temp = (const float*)d_in[3];
  const float* wq = (const float*)d_in[4];
  const float* wk = (const float*)d_in[5];
  const float* wv = (const float*)d_in[6];
  const float* dw[9];
  for (int i = 0; i < 9; i++) dw[i] = (const float*)d_in[7 + i];
  const float* attn_po = (const float*)d_in[16];
  const float* ln2_w = (const float*)d_in[17];
  const float* ln2_b = (const float*)d_in[18];
  const float* ffn_in = (const float*)d_in[19];
  const float* ffn_dw[3] = {(const float*)d_in[20], (const float*)d_in[21],
                            (const float*)d_in[22]};
  const float* ffn_po = (const float*)d_in[23];
  float* out = (float*)d_out;

  // ---- workspace layout: peak 128 MiB + 72 KiB, lifetime-aliased ----
  const size_t MB = (size_t)1 << 20;
  char* wsb = (char*)d_ws;
  float* xn = (float*)(wsb + 0 * MB);
  float* q0 = (float*)(wsb + 16 * MB);
  float* k0 = (float*)(wsb + 32 * MB);
  float* v0 = (float*)(wsb + 48 * MB);
  float* qd = (float*)(wsb + 64 * MB);
  float* kd = (float*)(wsb + 80 * MB);
  float* vd = (float*)(wsb + 96 * MB);
  float* x2 = (float*)(wsb + 112 * MB);
  float* invn = (float*)(wsb + 128 * MB);               // 8 KiB
  float* as_buf = (float*)(wsb + 128 * MB + 8 * 1024);  // 64 KiB
  float* osb = xn;
  float* xn2 = xn;
  float* part = xn;  // 4 MB partial-score buffer; dead before osb is written
  __hip_bfloat16* xin = (__hip_bfloat16*)(wsb + 16 * MB);    // 64 MB
  __hip_bfloat16* gated = (__hip_bfloat16*)(wsb + 80 * MB);  // 32 MB

  const int ln_grid = (B_ * HW_) / 256;                  // 128
  const int g128 = B_ * (C_ / 64) * 64;                  // 1024 (cout=128)
  const int g1024 = B_ * (1024 / 64) * 64;               // 8192 (cout=1024)
  const dim3 dwt_grid(B_ * C_ * 2, 3);                   // 2048 x 3
  const int ffg_grid = B_ * 512 * 2;                     // 8192
  const dim3 att_grid(B_ * HEADS_, 16);                  // 64 x 16

  // ---- attention branch ----
  ln_ch<<<ln_grid, 256, 0, stream>>>(x, ln1_w, ln1_b, xn);
  conv1x1_m<float, float><<<g128, 256, 0, stream>>>(xn, wq, nullptr, q0, C_, C_, C_, 0);
  conv1x1_m<float, float><<<g128, 256, 0, stream>>>(xn, wk, nullptr, k0, C_, C_, C_, 0);
  conv1x1_m<float, float><<<g128, 256, 0, stream>>>(xn, wv, nullptr, v0, C_, C_, C_, 0);

  for (int s = 0; s < 3; s++) {
    if (s == 0)
      dwconv_d<3><<<dwt_grid, 256, 0, stream>>>(q0, k0, v0, dw[0], dw[1], dw[2], qd, kd, vd);
    else if (s == 1)
      dwconv_d<5><<<dwt_grid, 256, 0, stream>>>(q0, k0, v0, dw[3], dw[4], dw[5], qd, kd, vd);
    else
      dwconv_d<7><<<dwt_grid, 256, 0, stream>>>(q0, k0, v0, dw[6], dw[7], dw[8], qd, kd, vd);
    l2_invnorm<<<2048, 256, 0, stream>>>(qd, kd, invn);
    attn_score_part<<<att_grid, 256, 0, stream>>>(qd, kd, part);
    attn_softmax<<<B_ * HEADS_, 256, 0, stream>>>(part, invn, temp, as_buf);
    attn_pv<<<att_grid, 256, 0, stream>>>(vd, as_buf, osb);
    conv1x1_m<float, float><<<g128, 256, 0, stream>>>(
        osb, attn_po + s * C_, (s == 0) ? x : nullptr, x2, C_, C_, 3 * C_, s == 0 ? 0 : 1);
  }

  // ---- FFN branch ----
  ln_ch<<<ln_grid, 256, 0, stream>>>(x2, ln2_w, ln2_b, xn2);
  conv1x1_m<float, __hip_bfloat16><<<g1024, 256, 0, stream>>>(
      xn2, ffn_in, nullptr, xin, C_, 1024, C_, 0);

  for (int s = 0; s < 3; s++) {
    if (s == 0)
      ffn_dwgate_d<3><<<ffg_grid, 256, 0, stream>>>(xin, ffn_dw[0], gated);
    else if (s == 1)
      ffn_dwgate_d<5><<<ffg_grid, 256, 0, stream>>>(xin, ffn_dw[1], gated);
    else
      ffn_dwgate_d<7><<<ffg_grid, 256, 0, stream>>>(xin, ffn_dw[2], gated);
    conv1x1_m<__hip_bfloat16, float><<<g128, 256, 0, stream>>>(
        gated, ffn_po + s * 512, (s == 0) ? x2 : nullptr, out, 512, C_, 3 * HID_,
        s == 0 ? 0 : 1);
  }
  (void)in_sizes; (void)n_in; (void)out_size; (void)ws_size;
}

// Round 11
// 582.311 us; speedup vs baseline: 2.1158x; 1.0344x over previous
//
#include <hip/hip_runtime.h>
#include <hip/hip_bf16.h>
#include <math.h>

#define B_ 8
#define C_ 128
#define H_ 64
#define W_ 64
#define HW_ 4096
#define HEADS_ 8
#define CH_ 16
#define HID_ 512

typedef unsigned short ushort_t;
struct __attribute__((aligned(8))) us4 { ushort_t x, y, z, w; };

typedef __attribute__((ext_vector_type(8))) short bf16x8;
typedef __attribute__((ext_vector_type(4))) float f32x4;

__device__ __forceinline__ float bf2f(ushort_t u) {
  return __uint_as_float(((unsigned int)u) << 16);
}
__device__ __forceinline__ ushort_t f2bu(float f) {
  __hip_bfloat16 h = __float2bfloat16(f);
  return *reinterpret_cast<ushort_t*>(&h);
}
__device__ __forceinline__ float toF(float v) { return v; }
__device__ __forceinline__ float toF(__hip_bfloat16 v) { return __bfloat162float(v); }
__device__ __forceinline__ void storeF(float* p, float v) { *p = v; }
__device__ __forceinline__ void storeF(__hip_bfloat16* p, float v) { *p = __float2bfloat16(v); }

// tanh-GELU: max dev from exact erf-GELU ~1e-3, straight-line (~10 VALU ops)
__device__ __forceinline__ float gelu_t(float x) {
  float z = 0.7978845608f * fmaf(0.044715f * x, x * x, x);
  float e = __expf(2.f * z);
  float th = 1.f - 2.f / (e + 1.f);
  return 0.5f * x * (1.f + th);
}

// ---------------- LayerNorm over channel dim ----------------
__global__ __launch_bounds__(256) void ln_ch(const float* __restrict__ x,
                                             const float* __restrict__ w,
                                             const float* __restrict__ b,
                                             float* __restrict__ out) {
  int p = blockIdx.x * 256 + threadIdx.x;  // over B*HW
  int bi = p >> 12;
  int pos = p & (HW_ - 1);
  const float* xb = x + (size_t)bi * C_ * HW_ + pos;
  float s = 0.f, ss = 0.f;
  for (int c = 0; c < C_; c++) {
    float v = xb[(size_t)c * HW_];
    s += v;
    ss = fmaf(v, v, ss);
  }
  float mu = s * (1.f / C_);
  float var = ss * (1.f / C_) - mu * mu;
  float inv = rsqrtf(var + 1e-5f);
  float* ob = out + (size_t)bi * C_ * HW_ + pos;
  for (int c = 0; c < C_; c++) {
    ob[(size_t)c * HW_] = (xb[(size_t)c * HW_] - mu) * inv * w[c] + b[c];
  }
}

// ---------------- vector load/store helpers ----------------
__device__ __forceinline__ void load4f(const float* p, float* v) {
  float4 t = *(const float4*)p;
  v[0] = t.x; v[1] = t.y; v[2] = t.z; v[3] = t.w;
}
__device__ __forceinline__ void load4f(const __hip_bfloat16* p, float* v) {
  us4 t = *(const us4*)p;
  v[0] = bf2f(t.x); v[1] = bf2f(t.y); v[2] = bf2f(t.z); v[3] = bf2f(t.w);
}
__device__ __forceinline__ void store4f(float* p, const float* v) {
  float4 t; t.x = v[0]; t.y = v[1]; t.z = v[2]; t.w = v[3];
  *(float4*)p = t;
}
__device__ __forceinline__ void store4f(__hip_bfloat16* p, const float* v) {
  us4 t; t.x = f2bu(v[0]); t.y = f2bu(v[1]); t.z = f2bu(v[2]); t.w = f2bu(v[3]);
  *(us4*)p = t;
}

// load 16-elem window rv[j] = row[cb-4+j], zero-padded outside [0,64)
__device__ __forceinline__ void loadrow_bf(const __hip_bfloat16* __restrict__ rowp,
                                           int cb, float* rv) {
#pragma unroll
  for (int b = 0; b < 4; b++) {
    int co = cb - 4 + b * 4;
    if ((unsigned)co <= 60u) {
      us4 t = *(const us4*)(rowp + co);
      rv[b * 4 + 0] = bf2f(t.x); rv[b * 4 + 1] = bf2f(t.y);
      rv[b * 4 + 2] = bf2f(t.z); rv[b * 4 + 3] = bf2f(t.w);
    } else {
      rv[b * 4 + 0] = 0.f; rv[b * 4 + 1] = 0.f;
      rv[b * 4 + 2] = 0.f; rv[b * 4 + 3] = 0.f;
    }
  }
}
__device__ __forceinline__ void loadrow_f(const float* __restrict__ rowp,
                                          int cb, float* rv) {
#pragma unroll
  for (int b = 0; b < 4; b++) {
    int co = cb - 4 + b * 4;
    if ((unsigned)co <= 60u) {
      float4 t = *(const float4*)(rowp + co);
      rv[b * 4 + 0] = t.x; rv[b * 4 + 1] = t.y;
      rv[b * 4 + 2] = t.z; rv[b * 4 + 3] = t.w;
    } else {
      rv[b * 4 + 0] = 0.f; rv[b * 4 + 1] = 0.f;
      rv[b * 4 + 2] = 0.f; rv[b * 4 + 3] = 0.f;
    }
  }
}

// ------- conv1x1 as bf16 MFMA GEMM: Out[cout][HW] = W[cout][cin] @ In[cin][HW] -------
template <typename Tin, typename Tout>
__global__ __launch_bounds__(256) void conv1x1_m(const Tin* __restrict__ in,
                                                 const float* __restrict__ wt,
                                                 const float* __restrict__ resid,
                                                 Tout* __restrict__ out,
                                                 int cin, int cout, int wstride,
                                                 int accum) {
  constexpr int ST = 68;
  __shared__ ushort_t bsh[128 * ST];
  int tid = threadIdx.x;
  int lane = tid & 63;
  int wv = tid >> 6;
  int lrow = lane & 15;
  int lk = lane >> 4;
  int blk = blockIdx.x;
  int nb = blk & 63;
  int rest = blk >> 6;
  int mb = cout >> 6;
  int m = rest % mb;
  int bi = rest / mb;
  int n0 = nb << 6;
  int o0 = (m << 6) + wv * 16;

  f32x4 acc[4] = {{0.f, 0.f, 0.f, 0.f}, {0.f, 0.f, 0.f, 0.f},
                  {0.f, 0.f, 0.f, 0.f}, {0.f, 0.f, 0.f, 0.f}};

  int cl = tid >> 4;
  int j4 = tid & 15;
  for (int kc = 0; kc < cin; kc += 128) {
#pragma unroll
    for (int p = 0; p < 8; p++) {
      int c = p * 16 + cl;
      const Tin* src = in + ((size_t)bi * cin + kc + c) * HW_ + n0 + j4 * 4;
      us4 u;
      if constexpr (sizeof(Tin) == 4) {
        float4 v = *(const float4*)src;
        u.x = f2bu(v.x); u.y = f2bu(v.y); u.z = f2bu(v.z); u.w = f2bu(v.w);
      } else {
        u = *(const us4*)src;
      }
      *(us4*)&bsh[c * ST + j4 * 4] = u;
    }
    __syncthreads();
#pragma unroll
    for (int ks = 0; ks < 4; ks++) {
      const float* wr = wt + (size_t)(o0 + lrow) * wstride + kc + ks * 32 + lk * 8;
      float4 wa = *(const float4*)wr;
      float4 wb2 = *(const float4*)(wr + 4);
      bf16x8 af;
      af[0] = (short)f2bu(wa.x); af[1] = (short)f2bu(wa.y);
      af[2] = (short)f2bu(wa.z); af[3] = (short)f2bu(wa.w);
      af[4] = (short)f2bu(wb2.x); af[5] = (short)f2bu(wb2.y);
      af[6] = (short)f2bu(wb2.z); af[7] = (short)f2bu(wb2.w);
#pragma unroll
      for (int s = 0; s < 4; s++) {
        int rb = (ks * 32 + lk * 8) * ST + s * 16 + lrow;
        bf16x8 bf_;
#pragma unroll
        for (int j = 0; j < 8; j++) bf_[j] = (short)bsh[rb + j * ST];
        acc[s] = __builtin_amdgcn_mfma_f32_16x16x32_bf16(af, bf_, acc[s], 0, 0, 0);
      }
    }
    __syncthreads();
  }

  const float* rp = resid ? resid + (size_t)bi * cout * HW_ : nullptr;
  Tout* op = out + (size_t)bi * cout * HW_;
#pragma unroll
  for (int s = 0; s < 4; s++) {
#pragma unroll
    for (int r = 0; r < 4; r++) {
      int o = o0 + lk * 4 + r;
      int n = n0 + s * 16 + lrow;
      size_t off = (size_t)o * HW_ + n;
      float v = acc[s][r];
      if (rp) v += rp[off];
      if (accum) v += toF(op[off]);
      storeF(&op[off], v);
    }
  }
}

// ------- depthwise conv, direct-global vectorized windows, 8 out/thread -------
template <int K>
__global__ __launch_bounds__(256) void dwconv_d(const float* __restrict__ q0,
                                                const float* __restrict__ k0,
                                                const float* __restrict__ v0,
                                                const float* __restrict__ wq_,
                                                const float* __restrict__ wk_,
                                                const float* __restrict__ wv_,
                                                float* __restrict__ qd,
                                                float* __restrict__ kd,
                                                float* __restrict__ vd) {
  constexpr int P = K / 2;
  __shared__ float wsh[K * K];
  int sel = blockIdx.y;
  const float* in = (sel == 0) ? q0 : (sel == 1) ? k0 : v0;
  const float* wgt = (sel == 0) ? wq_ : (sel == 1) ? wk_ : wv_;
  float* outp = (sel == 0) ? qd : (sel == 1) ? kd : vd;
  int blk = blockIdx.x;  // B*C*2
  int half = blk & 1;
  int c = (blk >> 1) & (C_ - 1);
  int bi = blk >> 8;
  int tid = threadIdx.x;

  if (tid < K * K) wsh[tid] = wgt[(size_t)c * K * K + tid];
  __syncthreads();

  int r = tid >> 3;
  int cb = (tid & 7) << 3;
  int y = half * 32 + r;
  const float* plane = in + (size_t)(bi * C_ + c) * HW_;

  float a[8];
#pragma unroll
  for (int o = 0; o < 8; o++) a[o] = 0.f;
#pragma unroll
  for (int dy = 0; dy < K; dy++) {
    int gy = y + dy - P;
    if ((unsigned)gy < 64u) {
      float rv[16];
      loadrow_f(plane + gy * 64, cb, rv);
#pragma unroll
      for (int dx = 0; dx < K; dx++) {
        float wv = wsh[dy * K + dx];
#pragma unroll
        for (int o = 0; o < 8; o++) a[o] = fmaf(rv[o + dx + 4 - P], wv, a[o]);
      }
    }
  }
  float* ob = outp + (size_t)(bi * C_ + c) * HW_ + y * 64 + cb;
  store4f(ob, &a[0]);
  store4f(ob + 4, &a[4]);
}

// ------- FFN depthwise conv + GEGLU gate, 2x8 patch/thread, tanh-gelu -------
template <int K>
__global__ __launch_bounds__(256) void ffn_dwgate_p(const __hip_bfloat16* __restrict__ xin,
                                                    const float* __restrict__ w,
                                                    __hip_bfloat16* __restrict__ gated) {
  constexpr int P = K / 2;
  __shared__ float wsh[2 * K * K];
  int blk = blockIdx.x;  // B*512
  int i = blk & 511;
  int bi = blk >> 9;
  int tid = threadIdx.x;

  if (tid < 2 * K * K) {
    wsh[tid] = (tid < K * K) ? w[(size_t)i * K * K + tid]
                             : w[(size_t)(512 + i) * K * K + (tid - K * K)];
  }
  __syncthreads();

  int r2 = tid >> 3;          // 0..31
  int cb = (tid & 7) << 3;
  int y0 = r2 * 2;            // rows y0, y0+1
  const __hip_bfloat16* gin = xin + (size_t)(bi * 1024 + i) * HW_;
  const __hip_bfloat16* min_ = gin + (size_t)512 * HW_;

  float ge[16];
  // ---- gate plane: K+1 row loads serve 2 output rows ----
  {
    float a0[8], a1[8];
#pragma unroll
    for (int o = 0; o < 8; o++) { a0[o] = 0.f; a1[o] = 0.f; }
#pragma unroll
    for (int rr = 0; rr <= K; rr++) {  // gy = y0 - P + rr
      int gy = y0 - P + rr;
      if ((unsigned)gy < 64u) {
        float rv[16];
        loadrow_bf(gin + gy * 64, cb, rv);
        if (rr < K) {  // row0 tap dy=rr (compile-time)
          float wv;
#pragma unroll
          for (int dx = 0; dx < K; dx++) {
            wv = wsh[rr * K + dx];
#pragma unroll
            for (int o = 0; o < 8; o++) a0[o] = fmaf(rv[o + dx + 4 - P], wv, a0[o]);
          }
        }
        if (rr >= 1) {  // row1 tap dy=rr-1
          float wv;
#pragma unroll
          for (int dx = 0; dx < K; dx++) {
            wv = wsh[(rr - 1) * K + dx];
#pragma unroll
            for (int o = 0; o < 8; o++) a1[o] = fmaf(rv[o + dx + 4 - P], wv, a1[o]);
          }
        }
      }
    }
#pragma unroll
    for (int o = 0; o < 8; o++) { ge[o] = gelu_t(a0[o]); ge[8 + o] = gelu_t(a1[o]); }
  }

  // ---- mult plane ----
  float m0[8], m1[8];
#pragma unroll
  for (int o = 0; o < 8; o++) { m0[o] = 0.f; m1[o] = 0.f; }
#pragma unroll
  for (int rr = 0; rr <= K; rr++) {
    int gy = y0 - P + rr;
    if ((unsigned)gy < 64u) {
      float rv[16];
      loadrow_bf(min_ + gy * 64, cb, rv);
      if (rr < K) {
        float wv;
#pragma unroll
        for (int dx = 0; dx < K; dx++) {
          wv = wsh[K * K + rr * K + dx];
#pragma unroll
          for (int o = 0; o < 8; o++) m0[o] = fmaf(rv[o + dx + 4 - P], wv, m0[o]);
        }
      }
      if (rr >= 1) {
        float wv;
#pragma unroll
        for (int dx = 0; dx < K; dx++) {
          wv = wsh[K * K + (rr - 1) * K + dx];
#pragma unroll
          for (int o = 0; o < 8; o++) m1[o] = fmaf(rv[o + dx + 4 - P], wv, m1[o]);
        }
      }
    }
  }
  __hip_bfloat16* gp = gated + (size_t)(bi * 512 + i) * HW_ + y0 * 64 + cb;
#pragma unroll
  for (int v = 0; v < 2; v++) {
    us4 t;
    t.x = f2bu(ge[v * 4 + 0] * m0[v * 4 + 0]);
    t.y = f2bu(ge[v * 4 + 1] * m0[v * 4 + 1]);
    t.z = f2bu(ge[v * 4 + 2] * m0[v * 4 + 2]);
    t.w = f2bu(ge[v * 4 + 3] * m0[v * 4 + 3]);
    *(us4*)(gp + v * 4) = t;
  }
  gp += 64;
#pragma unroll
  for (int v = 0; v < 2; v++) {
    us4 t;
    t.x = f2bu(ge[8 + v * 4 + 0] * m1[v * 4 + 0]);
    t.y = f2bu(ge[8 + v * 4 + 1] * m1[v * 4 + 1]);
    t.z = f2bu(ge[8 + v * 4 + 2] * m1[v * 4 + 2]);
    t.w = f2bu(ge[8 + v * 4 + 3] * m1[v * 4 + 3]);
    *(us4*)(gp + v * 4) = t;
  }
}

// ---------------- inverse L2 norms of qd and kd rows ----------------
__global__ __launch_bounds__(256) void l2_invnorm(const float* __restrict__ qd,
                                                  const float* __restrict__ kd,
                                                  float* __restrict__ invn) {
  int row = blockIdx.x;  // 0..2047; <1024 -> qd, else kd
  const float* src = (row < 1024) ? (qd + (size_t)row * HW_)
                                  : (kd + (size_t)(row - 1024) * HW_);
  float s = 0.f;
  for (int n = threadIdx.x; n < HW_; n += 256) {
    float v = src[n];
    s = fmaf(v, v, s);
  }
#pragma unroll
  for (int o = 32; o >= 1; o >>= 1) s += __shfl_xor(s, o, 64);
  __shared__ float red[4];
  if ((threadIdx.x & 63) == 0) red[threadIdx.x >> 6] = s;
  __syncthreads();
  if (threadIdx.x == 0) {
    float t = red[0] + red[1] + red[2] + red[3];
    invn[row] = 1.f / fmaxf(sqrtf(t), 1e-12f);
  }
}

// ---------------- attention: partial scores over 256-position chunks ----------------
__global__ __launch_bounds__(256) void attn_score_part(const float* __restrict__ qd,
                                                       const float* __restrict__ kd,
                                                       float* __restrict__ part) {
  constexpr int ST = 258;
  __shared__ float qs[16 * ST];
  __shared__ float ks[16 * ST];
  int bh = blockIdx.x;   // 64
  int ch = blockIdx.y;   // 16 chunks of 256
  int bi = bh >> 3;
  int h = bh & 7;
  int tid = threadIdx.x;
  int c = tid >> 4;
  int d = tid & 15;

  const float* qrow = qd + (size_t)(bi * C_ + h * CH_) * HW_ + ch * 256;
  const float* krow = kd + (size_t)(bi * C_ + h * CH_) * HW_ + ch * 256;
#pragma unroll
  for (int it = 0; it < 4; it++) {
    int idx = tid + it * 256;
    int r = idx >> 6, q4 = idx & 63;
    float4 qv = ((const float4*)(qrow + (size_t)r * HW_))[q4];
    float4 kv = ((const float4*)(krow + (size_t)r * HW_))[q4];
    float* qdst = &qs[r * ST + q4 * 4];
    float* kdst = &ks[r * ST + q4 * 4];
    qdst[0] = qv.x; qdst[1] = qv.y; qdst[2] = qv.z; qdst[3] = qv.w;
    kdst[0] = kv.x; kdst[1] = kv.y; kdst[2] = kv.z; kdst[3] = kv.w;
  }
  __syncthreads();

  const float* qp = &qs[c * ST];
  const float* kp = &ks[d * ST];
  float acc = 0.f;
#pragma unroll 8
  for (int j = 0; j < 256; j++) acc = fmaf(qp[j], kp[j], acc);
  part[((size_t)bh * 16 + ch) * 256 + tid] = acc;
}

// ---------------- attention: reduce partials + softmax ----------------
__global__ __launch_bounds__(256) void attn_softmax(const float* __restrict__ part,
                                                    const float* __restrict__ invn,
                                                    const float* __restrict__ temp,
                                                    float* __restrict__ as_buf) {
  int bh = blockIdx.x;  // 64
  int bi = bh >> 3;
  int h = bh & 7;
  int tid = threadIdx.x;
  int c = tid >> 4;
  int d = tid & 15;
  float s = 0.f;
  const float* pp = part + (size_t)bh * 16 * 256 + tid;
#pragma unroll
  for (int ch = 0; ch < 16; ch++) s += pp[ch * 256];
  float S = s * invn[bi * C_ + h * CH_ + c] * invn[1024 + bi * C_ + h * CH_ + d] *
            temp[h];
  float mx = S;
#pragma unroll
  for (int o = 8; o >= 1; o >>= 1) mx = fmaxf(mx, __shfl_xor(mx, o, 16));
  float e = expf(S - mx);
  float sm = e;
#pragma unroll
  for (int o = 8; o >= 1; o >>= 1) sm += __shfl_xor(sm, o, 16);
  as_buf[(size_t)bh * 256 + tid] = e / sm;
}

// ---------------- attention: PV over 256-position chunks ----------------
__global__ __launch_bounds__(256) void attn_pv(const float* __restrict__ vd,
                                               const float* __restrict__ as_buf,
                                               float* __restrict__ osb) {
  __shared__ float as[16][17];
  int bh = blockIdx.x;  // 64
  int ch = blockIdx.y;  // 16
  int bi = bh >> 3;
  int h = bh & 7;
  int tid = threadIdx.x;
  if (tid < 256) {
    int cc = tid >> 4, dd = tid & 15;
    as[cc][dd] = as_buf[(size_t)bh * 256 + tid];
  }
  __syncthreads();

  int n = ch * 256 + tid;
  const float* vrow = vd + (size_t)(bi * C_ + h * CH_) * HW_ + n;
  float o_[16];
#pragma unroll
  for (int cc = 0; cc < 16; cc++) o_[cc] = 0.f;
#pragma unroll
  for (int dd = 0; dd < 16; dd++) {
    float vv = vrow[(size_t)dd * HW_];
#pragma unroll
    for (int cc = 0; cc < 16; cc++) o_[cc] = fmaf(as[cc][dd], vv, o_[cc]);
  }
  float* ob = osb + (size_t)(bi * C_ + h * CH_) * HW_ + n;
#pragma unroll
  for (int cc = 0; cc < 16; cc++) ob[(size_t)cc * HW_] = o_[cc];
}

extern "C" void kernel_launch(void* const* d_in, const int* in_sizes, int n_in,
                              void* d_out, int out_size, void* d_ws, size_t ws_size,
                              hipStream_t stream) {
  const float* x = (const float*)d_in[0];
  const float* ln1_w = (const float*)d_in[1];
  const float* ln1_b = (const float*)d_in[2];
  const float* temp = (const float*)d_in[3];
  const float* wq = (const float*)d_in[4];
  const float* wk = (const float*)d_in[5];
  const float* wv = (const float*)d_in[6];
  const float* dw[9];
  for (int i = 0; i < 9; i++) dw[i] = (const float*)d_in[7 + i];
  const float* attn_po = (const float*)d_in[16];
  const float* ln2_w = (const float*)d_in[17];
  const float* ln2_b = (const float*)d_in[18];
  const float* ffn_in = (const float*)d_in[19];
  const float* ffn_dw[3] = {(const float*)d_in[20], (const float*)d_in[21],
                            (const float*)d_in[22]};
  const float* ffn_po = (const float*)d_in[23];
  float* out = (float*)d_out;

  // ---- workspace layout: peak 128 MiB + 72 KiB, lifetime-aliased ----
  const size_t MB = (size_t)1 << 20;
  char* wsb = (char*)d_ws;
  float* xn = (float*)(wsb + 0 * MB);
  float* q0 = (float*)(wsb + 16 * MB);
  float* k0 = (float*)(wsb + 32 * MB);
  float* v0 = (float*)(wsb + 48 * MB);
  float* qd = (float*)(wsb + 64 * MB);
  float* kd = (float*)(wsb + 80 * MB);
  float* vd = (float*)(wsb + 96 * MB);
  float* x2 = (float*)(wsb + 112 * MB);
  float* invn = (float*)(wsb + 128 * MB);               // 8 KiB
  float* as_buf = (float*)(wsb + 128 * MB + 8 * 1024);  // 64 KiB
  float* osb = xn;
  float* xn2 = xn;
  float* part = xn;  // 4 MB partial-score buffer; dead before osb is written
  __hip_bfloat16* xin = (__hip_bfloat16*)(wsb + 16 * MB);    // 64 MB
  __hip_bfloat16* gated = (__hip_bfloat16*)(wsb + 80 * MB);  // 32 MB

  const int ln_grid = (B_ * HW_) / 256;                  // 128
  const int g128 = B_ * (C_ / 64) * 64;                  // 1024 (cout=128)
  const int g1024 = B_ * (1024 / 64) * 64;               // 8192 (cout=1024)
  const dim3 dwt_grid(B_ * C_ * 2, 3);                   // 2048 x 3
  const int ffg_grid = B_ * 512;                         // 4096 (full plane/block)
  const dim3 att_grid(B_ * HEADS_, 16);                  // 64 x 16

  // ---- attention branch ----
  ln_ch<<<ln_grid, 256, 0, stream>>>(x, ln1_w, ln1_b, xn);
  conv1x1_m<float, float><<<g128, 256, 0, stream>>>(xn, wq, nullptr, q0, C_, C_, C_, 0);
  conv1x1_m<float, float><<<g128, 256, 0, stream>>>(xn, wk, nullptr, k0, C_, C_, C_, 0);
  conv1x1_m<float, float><<<g128, 256, 0, stream>>>(xn, wv, nullptr, v0, C_, C_, C_, 0);

  for (int s = 0; s < 3; s++) {
    if (s == 0)
      dwconv_d<3><<<dwt_grid, 256, 0, stream>>>(q0, k0, v0, dw[0], dw[1], dw[2], qd, kd, vd);
    else if (s == 1)
      dwconv_d<5><<<dwt_grid, 256, 0, stream>>>(q0, k0, v0, dw[3], dw[4], dw[5], qd, kd, vd);
    else
      dwconv_d<7><<<dwt_grid, 256, 0, stream>>>(q0, k0, v0, dw[6], dw[7], dw[8], qd, kd, vd);
    l2_invnorm<<<2048, 256, 0, stream>>>(qd, kd, invn);
    attn_score_part<<<att_grid, 256, 0, stream>>>(qd, kd, part);
    attn_softmax<<<B_ * HEADS_, 256, 0, stream>>>(part, invn, temp, as_buf);
    attn_pv<<<att_grid, 256, 0, stream>>>(vd, as_buf, osb);
    conv1x1_m<float, float><<<g128, 256, 0, stream>>>(
        osb, attn_po + s * C_, (s == 0) ? x : nullptr, x2, C_, C_, 3 * C_, s == 0 ? 0 : 1);
  }

  // ---- FFN branch ----
  ln_ch<<<ln_grid, 256, 0, stream>>>(x2, ln2_w, ln2_b, xn2);
  conv1x1_m<float, __hip_bfloat16><<<g1024, 256, 0, stream>>>(
      xn2, ffn_in, nullptr, xin, C_, 1024, C_, 0);

  for (int s = 0; s < 3; s++) {
    if (s == 0)
      ffn_dwgate_p<3><<<ffg_grid, 256, 0, stream>>>(xin, ffn_dw[0], gated);
    else if (s == 1)
      ffn_dwgate_p<5><<<ffg_grid, 256, 0, stream>>>(xin, ffn_dw[1], gated);
    else
      ffn_dwgate_p<7><<<ffg_grid, 256, 0, stream>>>(xin, ffn_dw[2], gated);
    conv1x1_m<__hip_bfloat16, float><<<g128, 256, 0, stream>>>(
        gated, ffn_po + s * 512, (s == 0) ? x2 : nullptr, out, 512, C_, 3 * HID_,
        s == 0 ? 0 : 1);
  }
  (void)in_sizes; (void)n_in; (void)out_size; (void)ws_size;
}

// Round 13
// 543.945 us; speedup vs baseline: 2.2650x; 1.0705x over previous
//
#include <hip/hip_runtime.h>
#include <hip/hip_bf16.h>
#include <math.h>

#define B_ 8
#define C_ 128
#define H_ 64
#define W_ 64
#define HW_ 4096
#define HEADS_ 8
#define CH_ 16
#define HID_ 512

typedef unsigned short ushort_t;
struct __attribute__((aligned(8))) us4 { ushort_t x, y, z, w; };

typedef __attribute__((ext_vector_type(8))) short bf16x8;
typedef __attribute__((ext_vector_type(4))) float f32x4;

__device__ __forceinline__ float bf2f(ushort_t u) {
  return __uint_as_float(((unsigned int)u) << 16);
}
__device__ __forceinline__ ushort_t f2bu(float f) {
  __hip_bfloat16 h = __float2bfloat16(f);
  return *reinterpret_cast<ushort_t*>(&h);
}
__device__ __forceinline__ float toF(float v) { return v; }
__device__ __forceinline__ float toF(__hip_bfloat16 v) { return __bfloat162float(v); }
__device__ __forceinline__ void storeF(float* p, float v) { *p = v; }
__device__ __forceinline__ void storeF(__hip_bfloat16* p, float v) { *p = __float2bfloat16(v); }

// tanh-GELU: max dev from exact erf-GELU ~1e-3, straight-line
__device__ __forceinline__ float gelu_t(float x) {
  float z = 0.7978845608f * fmaf(0.044715f * x, x * x, x);
  float e = __expf(2.f * z);
  float th = 1.f - 2.f / (e + 1.f);
  return 0.5f * x * (1.f + th);
}

// ---------------- LayerNorm over channel dim ----------------
__global__ __launch_bounds__(256) void ln_ch(const float* __restrict__ x,
                                             const float* __restrict__ w,
                                             const float* __restrict__ b,
                                             float* __restrict__ out) {
  int p = blockIdx.x * 256 + threadIdx.x;  // over B*HW
  int bi = p >> 12;
  int pos = p & (HW_ - 1);
  const float* xb = x + (size_t)bi * C_ * HW_ + pos;
  float s = 0.f, ss = 0.f;
  for (int c = 0; c < C_; c++) {
    float v = xb[(size_t)c * HW_];
    s += v;
    ss = fmaf(v, v, ss);
  }
  float mu = s * (1.f / C_);
  float var = ss * (1.f / C_) - mu * mu;
  float inv = rsqrtf(var + 1e-5f);
  float* ob = out + (size_t)bi * C_ * HW_ + pos;
  for (int c = 0; c < C_; c++) {
    ob[(size_t)c * HW_] = (xb[(size_t)c * HW_] - mu) * inv * w[c] + b[c];
  }
}

// ---------------- weight prep: fp32 -> bf16, all six matrices ----------------
__global__ __launch_bounds__(256) void cvt_w(const float* __restrict__ wq,
                                             const float* __restrict__ wk,
                                             const float* __restrict__ wv,
                                             const float* __restrict__ apo,
                                             const float* __restrict__ fin,
                                             const float* __restrict__ fpo,
                                             ushort_t* __restrict__ dst) {
  int id = blockIdx.x * 256 + threadIdx.x;
  const float* src;
  int off;
  if (id < 16384) { src = wq; off = id; }
  else if (id < 32768) { src = wk; off = id - 16384; }
  else if (id < 49152) { src = wv; off = id - 32768; }
  else if (id < 98304) { src = apo; off = id - 49152; }
  else if (id < 229376) { src = fin; off = id - 98304; }
  else if (id < 425984) { src = fpo; off = id - 229376; }
  else return;
  dst[id] = f2bu(src[off]);
}

// ---------------- vector load/store helpers ----------------
__device__ __forceinline__ void load4f(const float* p, float* v) {
  float4 t = *(const float4*)p;
  v[0] = t.x; v[1] = t.y; v[2] = t.z; v[3] = t.w;
}
__device__ __forceinline__ void load4f(const __hip_bfloat16* p, float* v) {
  us4 t = *(const us4*)p;
  v[0] = bf2f(t.x); v[1] = bf2f(t.y); v[2] = bf2f(t.z); v[3] = bf2f(t.w);
}
__device__ __forceinline__ void store4f(float* p, const float* v) {
  float4 t; t.x = v[0]; t.y = v[1]; t.z = v[2]; t.w = v[3];
  *(float4*)p = t;
}
__device__ __forceinline__ void store4f(__hip_bfloat16* p, const float* v) {
  us4 t; t.x = f2bu(v[0]); t.y = f2bu(v[1]); t.z = f2bu(v[2]); t.w = f2bu(v[3]);
  *(us4*)p = t;
}

// load 16-elem window rv[j] = row[cb-4+j], zero-padded outside [0,64)
__device__ __forceinline__ void loadrow_bf(const __hip_bfloat16* __restrict__ rowp,
                                           int cb, float* rv) {
#pragma unroll
  for (int b = 0; b < 4; b++) {
    int co = cb - 4 + b * 4;
    if ((unsigned)co <= 60u) {
      us4 t = *(const us4*)(rowp + co);
      rv[b * 4 + 0] = bf2f(t.x); rv[b * 4 + 1] = bf2f(t.y);
      rv[b * 4 + 2] = bf2f(t.z); rv[b * 4 + 3] = bf2f(t.w);
    } else {
      rv[b * 4 + 0] = 0.f; rv[b * 4 + 1] = 0.f;
      rv[b * 4 + 2] = 0.f; rv[b * 4 + 3] = 0.f;
    }
  }
}
__device__ __forceinline__ void loadrow_f(const float* __restrict__ rowp,
                                          int cb, float* rv) {
#pragma unroll
  for (int b = 0; b < 4; b++) {
    int co = cb - 4 + b * 4;
    if ((unsigned)co <= 60u) {
      float4 t = *(const float4*)(rowp + co);
      rv[b * 4 + 0] = t.x; rv[b * 4 + 1] = t.y;
      rv[b * 4 + 2] = t.z; rv[b * 4 + 3] = t.w;
    } else {
      rv[b * 4 + 0] = 0.f; rv[b * 4 + 1] = 0.f;
      rv[b * 4 + 2] = 0.f; rv[b * 4 + 3] = 0.f;
    }
  }
}

// ------- conv1x1 as bf16 MFMA GEMM: Out[cout][HW] = W[cout][cin] @ In[cin][HW] -------
// R11-proven structure (scalar ds_read_u16 B-frags, ST=68); bf16 weights pre-converted
// so the A-frag is two 8B loads with no v_cvt (bit-identical math to R11's inline cvt).
template <typename Tin, typename Tout>
__global__ __launch_bounds__(256) void conv1x1_m(const Tin* __restrict__ in,
                                                 const ushort_t* __restrict__ wtb,
                                                 const float* __restrict__ resid,
                                                 Tout* __restrict__ out,
                                                 int cin, int cout, int wstride,
                                                 int accum) {
  constexpr int ST = 68;
  __shared__ ushort_t bsh[128 * ST];
  int tid = threadIdx.x;
  int lane = tid & 63;
  int wid = tid >> 6;
  int lrow = lane & 15;
  int lk = lane >> 4;
  int blk = blockIdx.x;
  int nb = blk & 63;
  int rest = blk >> 6;
  int mb = cout >> 6;
  int m = rest % mb;
  int bi = rest / mb;
  int n0 = nb << 6;
  int o0 = (m << 6) + wid * 16;

  f32x4 acc[4] = {{0.f, 0.f, 0.f, 0.f}, {0.f, 0.f, 0.f, 0.f},
                  {0.f, 0.f, 0.f, 0.f}, {0.f, 0.f, 0.f, 0.f}};

  int cl = tid >> 4;
  int j4 = tid & 15;
  for (int kc = 0; kc < cin; kc += 128) {
#pragma unroll
    for (int p = 0; p < 8; p++) {
      int c = p * 16 + cl;
      const Tin* src = in + ((size_t)bi * cin + kc + c) * HW_ + n0 + j4 * 4;
      us4 u;
      if constexpr (sizeof(Tin) == 4) {
        float4 v = *(const float4*)src;
        u.x = f2bu(v.x); u.y = f2bu(v.y); u.z = f2bu(v.z); u.w = f2bu(v.w);
      } else {
        u = *(const us4*)src;
      }
      *(us4*)&bsh[c * ST + j4 * 4] = u;
    }
    __syncthreads();
#pragma unroll
    for (int ks = 0; ks < 4; ks++) {
      const ushort_t* wr = wtb + (size_t)(o0 + lrow) * wstride + kc + ks * 32 + lk * 8;
      us4 wlo = *(const us4*)wr;
      us4 whi = *(const us4*)(wr + 4);
      bf16x8 af;
      af[0] = (short)wlo.x; af[1] = (short)wlo.y;
      af[2] = (short)wlo.z; af[3] = (short)wlo.w;
      af[4] = (short)whi.x; af[5] = (short)whi.y;
      af[6] = (short)whi.z; af[7] = (short)whi.w;
#pragma unroll
      for (int s = 0; s < 4; s++) {
        int rb = (ks * 32 + lk * 8) * ST + s * 16 + lrow;
        bf16x8 bf_;
#pragma unroll
        for (int j = 0; j < 8; j++) bf_[j] = (short)bsh[rb + j * ST];
        acc[s] = __builtin_amdgcn_mfma_f32_16x16x32_bf16(af, bf_, acc[s], 0, 0, 0);
      }
    }
    __syncthreads();
  }

  const float* rp = resid ? resid + (size_t)bi * cout * HW_ : nullptr;
  Tout* op = out + (size_t)bi * cout * HW_;
#pragma unroll
  for (int s = 0; s < 4; s++) {
#pragma unroll
    for (int r = 0; r < 4; r++) {
      int o = o0 + lk * 4 + r;
      int n = n0 + s * 16 + lrow;
      size_t off = (size_t)o * HW_ + n;
      float v = acc[s][r];
      if (rp) v += rp[off];
      if (accum) v += toF(op[off]);
      storeF(&op[off], v);
    }
  }
}

// ------- depthwise conv, direct-global vectorized windows, 8 out/thread -------
template <int K>
__global__ __launch_bounds__(256) void dwconv_d(const float* __restrict__ q0,
                                                const float* __restrict__ k0,
                                                const float* __restrict__ v0,
                                                const float* __restrict__ wq_,
                                                const float* __restrict__ wk_,
                                                const float* __restrict__ wv_,
                                                float* __restrict__ qd,
                                                float* __restrict__ kd,
                                                float* __restrict__ vd) {
  constexpr int P = K / 2;
  __shared__ float wsh[K * K];
  int sel = blockIdx.y;
  const float* in = (sel == 0) ? q0 : (sel == 1) ? k0 : v0;
  const float* wgt = (sel == 0) ? wq_ : (sel == 1) ? wk_ : wv_;
  float* outp = (sel == 0) ? qd : (sel == 1) ? kd : vd;
  int blk = blockIdx.x;  // B*C*2
  int half = blk & 1;
  int c = (blk >> 1) & (C_ - 1);
  int bi = blk >> 8;
  int tid = threadIdx.x;

  if (tid < K * K) wsh[tid] = wgt[(size_t)c * K * K + tid];
  __syncthreads();

  int r = tid >> 3;
  int cb = (tid & 7) << 3;
  int y = half * 32 + r;
  const float* plane = in + (size_t)(bi * C_ + c) * HW_;

  float a[8];
#pragma unroll
  for (int o = 0; o < 8; o++) a[o] = 0.f;
#pragma unroll
  for (int dy = 0; dy < K; dy++) {
    int gy = y + dy - P;
    if ((unsigned)gy < 64u) {
      float rv[16];
      loadrow_f(plane + gy * 64, cb, rv);
#pragma unroll
      for (int dx = 0; dx < K; dx++) {
        float wv = wsh[dy * K + dx];
#pragma unroll
        for (int o = 0; o < 8; o++) a[o] = fmaf(rv[o + dx + 4 - P], wv, a[o]);
      }
    }
  }
  float* ob = outp + (size_t)(bi * C_ + c) * HW_ + y * 64 + cb;
  store4f(ob, &a[0]);
  store4f(ob + 4, &a[4]);
}

// ------- FFN depthwise conv + GEGLU gate, 2x8 patch/thread, tanh-gelu -------
template <int K>
__global__ __launch_bounds__(256) void ffn_dwgate_p(const __hip_bfloat16* __restrict__ xin,
                                                    const float* __restrict__ w,
                                                    __hip_bfloat16* __restrict__ gated) {
  constexpr int P = K / 2;
  __shared__ float wsh[2 * K * K];
  int blk = blockIdx.x;  // B*512
  int i = blk & 511;
  int bi = blk >> 9;
  int tid = threadIdx.x;

  if (tid < 2 * K * K) {
    wsh[tid] = (tid < K * K) ? w[(size_t)i * K * K + tid]
                             : w[(size_t)(512 + i) * K * K + (tid - K * K)];
  }
  __syncthreads();

  int r2 = tid >> 3;          // 0..31
  int cb = (tid & 7) << 3;
  int y0 = r2 * 2;
  const __hip_bfloat16* gin = xin + (size_t)(bi * 1024 + i) * HW_;
  const __hip_bfloat16* min_ = gin + (size_t)512 * HW_;

  float ge[16];
  {
    float a0[8], a1[8];
#pragma unroll
    for (int o = 0; o < 8; o++) { a0[o] = 0.f; a1[o] = 0.f; }
#pragma unroll
    for (int rr = 0; rr <= K; rr++) {
      int gy = y0 - P + rr;
      if ((unsigned)gy < 64u) {
        float rv[16];
        loadrow_bf(gin + gy * 64, cb, rv);
        if (rr < K) {
          float wv;
#pragma unroll
          for (int dx = 0; dx < K; dx++) {
            wv = wsh[rr * K + dx];
#pragma unroll
            for (int o = 0; o < 8; o++) a0[o] = fmaf(rv[o + dx + 4 - P], wv, a0[o]);
          }
        }
        if (rr >= 1) {
          float wv;
#pragma unroll
          for (int dx = 0; dx < K; dx++) {
            wv = wsh[(rr - 1) * K + dx];
#pragma unroll
            for (int o = 0; o < 8; o++) a1[o] = fmaf(rv[o + dx + 4 - P], wv, a1[o]);
          }
        }
      }
    }
#pragma unroll
    for (int o = 0; o < 8; o++) { ge[o] = gelu_t(a0[o]); ge[8 + o] = gelu_t(a1[o]); }
  }

  float m0[8], m1[8];
#pragma unroll
  for (int o = 0; o < 8; o++) { m0[o] = 0.f; m1[o] = 0.f; }
#pragma unroll
  for (int rr = 0; rr <= K; rr++) {
    int gy = y0 - P + rr;
    if ((unsigned)gy < 64u) {
      float rv[16];
      loadrow_bf(min_ + gy * 64, cb, rv);
      if (rr < K) {
        float wv;
#pragma unroll
        for (int dx = 0; dx < K; dx++) {
          wv = wsh[K * K + rr * K + dx];
#pragma unroll
          for (int o = 0; o < 8; o++) m0[o] = fmaf(rv[o + dx + 4 - P], wv, m0[o]);
        }
      }
      if (rr >= 1) {
        float wv;
#pragma unroll
        for (int dx = 0; dx < K; dx++) {
          wv = wsh[K * K + (rr - 1) * K + dx];
#pragma unroll
          for (int o = 0; o < 8; o++) m1[o] = fmaf(rv[o + dx + 4 - P], wv, m1[o]);
        }
      }
    }
  }
  __hip_bfloat16* gp = gated + (size_t)(bi * 512 + i) * HW_ + y0 * 64 + cb;
#pragma unroll
  for (int v = 0; v < 2; v++) {
    us4 t;
    t.x = f2bu(ge[v * 4 + 0] * m0[v * 4 + 0]);
    t.y = f2bu(ge[v * 4 + 1] * m0[v * 4 + 1]);
    t.z = f2bu(ge[v * 4 + 2] * m0[v * 4 + 2]);
    t.w = f2bu(ge[v * 4 + 3] * m0[v * 4 + 3]);
    *(us4*)(gp + v * 4) = t;
  }
  gp += 64;
#pragma unroll
  for (int v = 0; v < 2; v++) {
    us4 t;
    t.x = f2bu(ge[8 + v * 4 + 0] * m1[v * 4 + 0]);
    t.y = f2bu(ge[8 + v * 4 + 1] * m1[v * 4 + 1]);
    t.z = f2bu(ge[8 + v * 4 + 2] * m1[v * 4 + 2]);
    t.w = f2bu(ge[8 + v * 4 + 3] * m1[v * 4 + 3]);
    *(us4*)(gp + v * 4) = t;
  }
}

// ---------------- inverse L2 norms of qd and kd rows ----------------
__global__ __launch_bounds__(256) void l2_invnorm(const float* __restrict__ qd,
                                                  const float* __restrict__ kd,
                                                  float* __restrict__ invn) {
  int row = blockIdx.x;  // 0..2047; <1024 -> qd, else kd
  const float* src = (row < 1024) ? (qd + (size_t)row * HW_)
                                  : (kd + (size_t)(row - 1024) * HW_);
  float s = 0.f;
  for (int n = threadIdx.x; n < HW_; n += 256) {
    float v = src[n];
    s = fmaf(v, v, s);
  }
#pragma unroll
  for (int o = 32; o >= 1; o >>= 1) s += __shfl_xor(s, o, 64);
  __shared__ float red[4];
  if ((threadIdx.x & 63) == 0) red[threadIdx.x >> 6] = s;
  __syncthreads();
  if (threadIdx.x == 0) {
    float t = red[0] + red[1] + red[2] + red[3];
    invn[row] = 1.f / fmaxf(sqrtf(t), 1e-12f);
  }
}

// ---------------- attention: partial scores over 256-position chunks ----------------
__global__ __launch_bounds__(256) void attn_score_part(const float* __restrict__ qd,
                                                       const float* __restrict__ kd,
                                                       float* __restrict__ part) {
  constexpr int ST = 258;
  __shared__ float qs[16 * ST];
  __shared__ float ks[16 * ST];
  int bh = blockIdx.x;   // 64
  int ch = blockIdx.y;   // 16 chunks of 256
  int bi = bh >> 3;
  int h = bh & 7;
  int tid = threadIdx.x;
  int c = tid >> 4;
  int d = tid & 15;

  const float* qrow = qd + (size_t)(bi * C_ + h * CH_) * HW_ + ch * 256;
  const float* krow = kd + (size_t)(bi * C_ + h * CH_) * HW_ + ch * 256;
#pragma unroll
  for (int it = 0; it < 4; it++) {
    int idx = tid + it * 256;
    int r = idx >> 6, q4 = idx & 63;
    float4 qv = ((const float4*)(qrow + (size_t)r * HW_))[q4];
    float4 kv = ((const float4*)(krow + (size_t)r * HW_))[q4];
    float* qdst = &qs[r * ST + q4 * 4];
    float* kdst = &ks[r * ST + q4 * 4];
    qdst[0] = qv.x; qdst[1] = qv.y; qdst[2] = qv.z; qdst[3] = qv.w;
    kdst[0] = kv.x; kdst[1] = kv.y; kdst[2] = kv.z; kdst[3] = kv.w;
  }
  __syncthreads();

  const float* qp = &qs[c * ST];
  const float* kp = &ks[d * ST];
  float acc = 0.f;
#pragma unroll 8
  for (int j = 0; j < 256; j++) acc = fmaf(qp[j], kp[j], acc);
  part[((size_t)bh * 16 + ch) * 256 + tid] = acc;
}

// ---------------- attention: reduce partials + softmax ----------------
__global__ __launch_bounds__(256) void attn_softmax(const float* __restrict__ part,
                                                    const float* __restrict__ invn,
                                                    const float* __restrict__ temp,
                                                    float* __restrict__ as_buf) {
  int bh = blockIdx.x;  // 64
  int bi = bh >> 3;
  int h = bh & 7;
  int tid = threadIdx.x;
  int c = tid >> 4;
  int d = tid & 15;
  float s = 0.f;
  const float* pp = part + (size_t)bh * 16 * 256 + tid;
#pragma unroll
  for (int ch = 0; ch < 16; ch++) s += pp[ch * 256];
  float S = s * invn[bi * C_ + h * CH_ + c] * invn[1024 + bi * C_ + h * CH_ + d] *
            temp[h];
  float mx = S;
#pragma unroll
  for (int o = 8; o >= 1; o >>= 1) mx = fmaxf(mx, __shfl_xor(mx, o, 16));
  float e = expf(S - mx);
  float sm = e;
#pragma unroll
  for (int o = 8; o >= 1; o >>= 1) sm += __shfl_xor(sm, o, 16);
  as_buf[(size_t)bh * 256 + tid] = e / sm;
}

// ---------------- attention: PV over 256-position chunks ----------------
__global__ __launch_bounds__(256) void attn_pv(const float* __restrict__ vd,
                                               const float* __restrict__ as_buf,
                                               float* __restrict__ osb) {
  __shared__ float as[16][17];
  int bh = blockIdx.x;  // 64
  int ch = blockIdx.y;  // 16
  int bi = bh >> 3;
  int h = bh & 7;
  int tid = threadIdx.x;
  if (tid < 256) {
    int cc = tid >> 4, dd = tid & 15;
    as[cc][dd] = as_buf[(size_t)bh * 256 + tid];
  }
  __syncthreads();

  int n = ch * 256 + tid;
  const float* vrow = vd + (size_t)(bi * C_ + h * CH_) * HW_ + n;
  float o_[16];
#pragma unroll
  for (int cc = 0; cc < 16; cc++) o_[cc] = 0.f;
#pragma unroll
  for (int dd = 0; dd < 16; dd++) {
    float vv = vrow[(size_t)dd * HW_];
#pragma unroll
    for (int cc = 0; cc < 16; cc++) o_[cc] = fmaf(as[cc][dd], vv, o_[cc]);
  }
  float* ob = osb + (size_t)(bi * C_ + h * CH_) * HW_ + n;
#pragma unroll
  for (int cc = 0; cc < 16; cc++) ob[(size_t)cc * HW_] = o_[cc];
}

extern "C" void kernel_launch(void* const* d_in, const int* in_sizes, int n_in,
                              void* d_out, int out_size, void* d_ws, size_t ws_size,
                              hipStream_t stream) {
  const float* x = (const float*)d_in[0];
  const float* ln1_w = (const float*)d_in[1];
  const float* ln1_b = (const float*)d_in[2];
  const float* temp = (const float*)d_in[3];
  const float* wq = (const float*)d_in[4];
  const float* wk = (const float*)d_in[5];
  const float* wv = (const float*)d_in[6];
  const float* dw[9];
  for (int i = 0; i < 9; i++) dw[i] = (const float*)d_in[7 + i];
  const float* attn_po = (const float*)d_in[16];
  const float* ln2_w = (const float*)d_in[17];
  const float* ln2_b = (const float*)d_in[18];
  const float* ffn_in = (const float*)d_in[19];
  const float* ffn_dw[3] = {(const float*)d_in[20], (const float*)d_in[21],
                            (const float*)d_in[22]};
  const float* ffn_po = (const float*)d_in[23];
  float* out = (float*)d_out;

  // ---- workspace layout: peak ~129 MiB, lifetime-aliased ----
  const size_t MB = (size_t)1 << 20;
  char* wsb = (char*)d_ws;
  float* xn = (float*)(wsb + 0 * MB);
  float* q0 = (float*)(wsb + 16 * MB);
  float* k0 = (float*)(wsb + 32 * MB);
  float* v0 = (float*)(wsb + 48 * MB);
  float* qd = (float*)(wsb + 64 * MB);
  float* kd = (float*)(wsb + 80 * MB);
  float* vd = (float*)(wsb + 96 * MB);
  float* x2 = (float*)(wsb + 112 * MB);
  float* invn = (float*)(wsb + 128 * MB);               // 8 KiB
  float* as_buf = (float*)(wsb + 128 * MB + 8 * 1024);  // 64 KiB
  ushort_t* wbuf = (ushort_t*)(wsb + 128 * MB + 80 * 1024);  // 832 KiB bf16 weights
  float* osb = xn;
  float* xn2 = xn;
  float* part = xn;  // 4 MB partial-score buffer; dead before osb is written
  __hip_bfloat16* xin = (__hip_bfloat16*)(wsb + 16 * MB);    // 64 MB
  __hip_bfloat16* gated = (__hip_bfloat16*)(wsb + 80 * MB);  // 32 MB

  const ushort_t* wb_q = wbuf;
  const ushort_t* wb_k = wbuf + 16384;
  const ushort_t* wb_v = wbuf + 32768;
  const ushort_t* wb_apo = wbuf + 49152;
  const ushort_t* wb_fin = wbuf + 98304;
  const ushort_t* wb_fpo = wbuf + 229376;

  const int ln_grid = (B_ * HW_) / 256;                  // 128
  const int g128 = B_ * (C_ / 64) * 64;                  // 1024 (cout=128)
  const int g1024 = B_ * (1024 / 64) * 64;               // 8192 (cout=1024)
  const dim3 dwt_grid(B_ * C_ * 2, 3);                   // 2048 x 3
  const int ffg_grid = B_ * 512;                         // 4096
  const dim3 att_grid(B_ * HEADS_, 16);                  // 64 x 16

  // ---- weight prep (bf16) ----
  cvt_w<<<1664, 256, 0, stream>>>(wq, wk, wv, attn_po, ffn_in, ffn_po, wbuf);

  // ---- attention branch ----
  ln_ch<<<ln_grid, 256, 0, stream>>>(x, ln1_w, ln1_b, xn);
  conv1x1_m<float, float><<<g128, 256, 0, stream>>>(xn, wb_q, nullptr, q0, C_, C_, C_, 0);
  conv1x1_m<float, float><<<g128, 256, 0, stream>>>(xn, wb_k, nullptr, k0, C_, C_, C_, 0);
  conv1x1_m<float, float><<<g128, 256, 0, stream>>>(xn, wb_v, nullptr, v0, C_, C_, C_, 0);

  for (int s = 0; s < 3; s++) {
    if (s == 0)
      dwconv_d<3><<<dwt_grid, 256, 0, stream>>>(q0, k0, v0, dw[0], dw[1], dw[2], qd, kd, vd);
    else if (s == 1)
      dwconv_d<5><<<dwt_grid, 256, 0, stream>>>(q0, k0, v0, dw[3], dw[4], dw[5], qd, kd, vd);
    else
      dwconv_d<7><<<dwt_grid, 256, 0, stream>>>(q0, k0, v0, dw[6], dw[7], dw[8], qd, kd, vd);
    l2_invnorm<<<2048, 256, 0, stream>>>(qd, kd, invn);
    attn_score_part<<<att_grid, 256, 0, stream>>>(qd, kd, part);
    attn_softmax<<<B_ * HEADS_, 256, 0, stream>>>(part, invn, temp, as_buf);
    attn_pv<<<att_grid, 256, 0, stream>>>(vd, as_buf, osb);
    conv1x1_m<float, float><<<g128, 256, 0, stream>>>(
        osb, wb_apo + s * C_, (s == 0) ? x : nullptr, x2, C_, C_, 3 * C_, s == 0 ? 0 : 1);
  }

  // ---- FFN branch ----
  ln_ch<<<ln_grid, 256, 0, stream>>>(x2, ln2_w, ln2_b, xn2);
  conv1x1_m<float, __hip_bfloat16><<<g1024, 256, 0, stream>>>(
      xn2, wb_fin, nullptr, xin, C_, 1024, C_, 0);

  for (int s = 0; s < 3; s++) {
    if (s == 0)
      ffn_dwgate_p<3><<<ffg_grid, 256, 0, stream>>>(xin, ffn_dw[0], gated);
    else if (s == 1)
      ffn_dwgate_p<5><<<ffg_grid, 256, 0, stream>>>(xin, ffn_dw[1], gated);
    else
      ffn_dwgate_p<7><<<ffg_grid, 256, 0, stream>>>(xin, ffn_dw[2], gated);
    conv1x1_m<__hip_bfloat16, float><<<g128, 256, 0, stream>>>(
        gated, wb_fpo + s * 512, (s == 0) ? x2 : nullptr, out, 512, C_, 3 * HID_,
        s == 0 ? 0 : 1);
  }
  (void)in_sizes; (void)n_in; (void)out_size; (void)ws_size;
}